// Round 1
// baseline (915.359 us; speedup 1.0000x reference)
//
#include <hip/hip_runtime.h>

#define KDIM 128
#define NTOT (KDIM * KDIM * KDIM)

static constexpr float PI_F = 3.14159265358979323846f;
static constexpr float TWO_PI_F = 6.28318530717958647692f;
static constexpr float KE_F = 14.3996f;
static constexpr float ALPHA_F = 0.35f;

__device__ __forceinline__ int brev7(int i) { return (int)(__brev((unsigned)i) >> 25); }

__device__ __forceinline__ void inv3x3(const float* c, float* inv, float* adet) {
    float a00 = c[0], a01 = c[1], a02 = c[2];
    float a10 = c[3], a11 = c[4], a12 = c[5];
    float a20 = c[6], a21 = c[7], a22 = c[8];
    float det = a00 * (a11 * a22 - a12 * a21) - a01 * (a10 * a22 - a12 * a20) +
                a02 * (a10 * a21 - a11 * a20);
    float id = 1.0f / det;
    inv[0] = (a11 * a22 - a12 * a21) * id;
    inv[1] = (a02 * a21 - a01 * a22) * id;
    inv[2] = (a01 * a12 - a02 * a11) * id;
    inv[3] = (a12 * a20 - a10 * a22) * id;
    inv[4] = (a00 * a22 - a02 * a20) * id;
    inv[5] = (a02 * a10 - a00 * a12) * id;
    inv[6] = (a10 * a21 - a11 * a20) * id;
    inv[7] = (a01 * a20 - a00 * a21) * id;
    inv[8] = (a00 * a11 - a01 * a10) * id;
    *adet = fabsf(det);
}

// Cardinal B-spline M_4 weights at f in [0,1) (leftmost node first) + d/du.
__device__ __forceinline__ void bspline4(float f, float* w, float* dw) {
    float f2 = f * f, f3 = f2 * f;
    float omf = 1.0f - f;
    w[0] = omf * omf * omf * (1.0f / 6.0f);
    w[1] = (3.0f * f3 - 6.0f * f2 + 4.0f) * (1.0f / 6.0f);
    w[2] = (-3.0f * f3 + 3.0f * f2 + 3.0f * f + 1.0f) * (1.0f / 6.0f);
    w[3] = f3 * (1.0f / 6.0f);
    dw[0] = -0.5f * omf * omf;
    dw[1] = 1.5f * f2 - 2.0f * f;
    dw[2] = -1.5f * f2 + f + 0.5f;
    dw[3] = 0.5f * f2;
}

__device__ __forceinline__ void atom_setup(const float* __restrict__ pos, const float* inv,
                                           int i, float wgt[3][4], float dwg[3][4],
                                           int idx[3][4]) {
    float p0 = pos[3 * i], p1 = pos[3 * i + 1], p2 = pos[3 * i + 2];
#pragma unroll
    for (int d = 0; d < 3; d++) {
        float fr = p0 * inv[d] + p1 * inv[3 + d] + p2 * inv[6 + d];
        fr -= floorf(fr);
        float u = fr * (float)KDIM;
        float bs = floorf(u);
        float f = u - bs;
        bspline4(f, wgt[d], dwg[d]);
        int b = (int)bs;
#pragma unroll
        for (int j = 0; j < 4; j++) idx[d][j] = (b - 3 + j + KDIM) & (KDIM - 1);
    }
}

// ---------------- charge spreading + sum(q^2) ----------------
__global__ __launch_bounds__(256) void spread_kernel(const float* __restrict__ pos,
                                                     const float* __restrict__ chg,
                                                     const float* __restrict__ cell,
                                                     float2* __restrict__ C,
                                                     double* __restrict__ esums, int n) {
    int i = blockIdx.x * blockDim.x + threadIdx.x;
    float q2 = 0.0f;
    if (i < n) {
        float inv[9], det;
        inv3x3(cell, inv, &det);
        float qi = chg[i];
        q2 = qi * qi;
        float wgt[3][4], dwg[3][4];
        int idx[3][4];
        atom_setup(pos, inv, i, wgt, dwg, idx);
#pragma unroll
        for (int j0 = 0; j0 < 4; j0++) {
            int r0 = idx[0][j0] << 14;
            float qwx = qi * wgt[0][j0];
#pragma unroll
            for (int j1 = 0; j1 < 4; j1++) {
                int r1 = r0 + (idx[1][j1] << 7);
                float qwxy = qwx * wgt[1][j1];
#pragma unroll
                for (int j2 = 0; j2 < 4; j2++) {
                    atomicAdd(&C[r1 + idx[2][j2]].x, qwxy * wgt[2][j2]);
                }
            }
        }
    }
#pragma unroll
    for (int off = 32; off; off >>= 1) q2 += __shfl_down(q2, off);
    if ((threadIdx.x & 63) == 0) atomicAdd(&esums[1], (double)q2);
}

// ---------------- 128-point FFT on an LDS line (one wave, lanes l=0..63) ----------------
__device__ __forceinline__ void fft128(float2* b, int st, int off, int l, float sign) {
    int i0 = brev7(l), i1 = brev7(l + 64);
    float2 r0 = b[i0 * st + off];
    float2 r1 = b[i1 * st + off];
    __syncthreads();
    b[l * st + off] = r0;
    b[(l + 64) * st + off] = r1;
    __syncthreads();
#pragma unroll
    for (int m = 1; m < 128; m <<= 1) {
        int pos = l & (m - 1);
        int bi = ((l & ~(m - 1)) << 1) | pos;
        float ang = sign * (PI_F / (float)m) * (float)pos;
        float sn, cs;
        __sincosf(ang, &sn, &cs);
        float2 E = b[bi * st + off];
        float2 O = b[(bi + m) * st + off];
        float2 t = make_float2(O.x * cs - O.y * sn, O.x * sn + O.y * cs);
        b[bi * st + off] = make_float2(E.x + t.x, E.y + t.y);
        b[(bi + m) * st + off] = make_float2(E.x - t.x, E.y - t.y);
        __syncthreads();
    }
}

// FFT along z (contiguous lines). 8 lines per block, one wave each.
__global__ __launch_bounds__(512) void fft_line_z(float2* __restrict__ C, float sign) {
    __shared__ float2 lds[8 * 128];
    int w = threadIdx.x >> 6, l = threadIdx.x & 63;
    int line = (blockIdx.x << 3) + w;
    float2* L = lds + (w << 7);
    int base = line << 7;
    L[l] = C[base + l];
    L[l + 64] = C[base + l + 64];
    __syncthreads();
    fft128(L, 1, 0, l, sign);
    C[base + l] = L[l];
    C[base + l + 64] = L[l + 64];
}

// FFT along a strided dim. Block handles 8 lines sharing 8 consecutive z.
// Line element e: C[p*OS + ll*LS + (z0+zt)], wave w computes line zt=w.
__global__ __launch_bounds__(512) void fft_line_t(float2* __restrict__ C, int LS, int OS,
                                                  float sign) {
    __shared__ float2 lds[128 * 9];
    int tid = threadIdx.x;
    int p = blockIdx.x >> 4;
    int z0 = (blockIdx.x & 15) << 3;
    int base = p * OS + z0;
#pragma unroll
    for (int kk = 0; kk < 2; kk++) {
        int e = tid + (kk << 9);
        int ll = e >> 3, zt = e & 7;
        lds[ll * 9 + zt] = C[base + ll * LS + zt];
    }
    __syncthreads();
    fft128(lds, 9, tid >> 6, tid & 63, sign);
#pragma unroll
    for (int kk = 0; kk < 2; kk++) {
        int e = tid + (kk << 9);
        int ll = e >> 3, zt = e & 7;
        C[base + ll * LS + zt] = lds[ll * 9 + zt];
    }
}

// ---------------- reciprocal-space scale + energy reduction ----------------
__device__ __forceinline__ float bmod2f(int x) {
    float th = (TWO_PI_F / (float)KDIM) * (float)x;
    float s1, c1, s2, c2;
    __sincosf(th, &s1, &c1);
    __sincosf(th + th, &s2, &c2);
    float dr = 0.16666667f + 0.66666667f * c1 + 0.16666667f * c2;
    float di = 0.66666667f * s1 + 0.16666667f * s2;
    float d2 = dr * dr + di * di;
    return 1.0f / fmaxf(d2, 1e-12f);
}

__global__ __launch_bounds__(256) void scale_kernel(float2* __restrict__ C,
                                                    const float* __restrict__ cell,
                                                    double* __restrict__ esums) {
    __shared__ float red[4];
    int idx = blockIdx.x * 256 + threadIdx.x;
    float inv[9], det;
    inv3x3(cell, inv, &det);
    int x = idx >> 14, y = (idx >> 7) & 127, z = idx & 127;
    float mx = (float)(x < 64 ? x : x - 128);
    float my = (float)(y < 64 ? y : y - 128);
    float mz = (float)(z < 64 ? z : z - 128);
    float kx = TWO_PI_F * (mx * inv[0] + my * inv[1] + mz * inv[2]);
    float ky = TWO_PI_F * (mx * inv[3] + my * inv[4] + mz * inv[5]);
    float kz = TWO_PI_F * (mx * inv[6] + my * inv[7] + mz * inv[8]);
    float k2 = kx * kx + ky * ky + kz * kz;
    float A = 0.0f;
    if (k2 > 0.0f) {
        A = __expf(-k2 / (4.0f * ALPHA_F * ALPHA_F)) / k2;
        A *= bmod2f(x) * bmod2f(y) * bmod2f(z);
    }
    float2 s = C[idx];
    float contrib = A * (s.x * s.x + s.y * s.y);
    C[idx] = make_float2(s.x * A, s.y * A);
#pragma unroll
    for (int off = 32; off; off >>= 1) contrib += __shfl_down(contrib, off);
    int w = threadIdx.x >> 6;
    if ((threadIdx.x & 63) == 0) red[w] = contrib;
    __syncthreads();
    if (threadIdx.x == 0) {
        float v = red[0] + red[1] + red[2] + red[3];
        atomicAdd(&esums[0], (double)v);
    }
}

// ---------------- energy finalize ----------------
__global__ void finalize_kernel(const double* __restrict__ esums,
                                const float* __restrict__ cell, float* __restrict__ out) {
    float inv[9], det;
    inv3x3(cell, inv, &det);
    double c = (double)KE_F * 2.0 * 3.14159265358979323846 / (double)det;
    double e = c * esums[0] -
               (double)KE_F * (double)ALPHA_F / 1.7724538509055160273 * esums[1];
    out[0] = (float)e;
}

// ---------------- force gather ----------------
__global__ __launch_bounds__(256) void gather_kernel(const float* __restrict__ pos,
                                                     const float* __restrict__ chg,
                                                     const float* __restrict__ cell,
                                                     const float2* __restrict__ C,
                                                     float* __restrict__ out, int n) {
    int i = blockIdx.x * blockDim.x + threadIdx.x;
    if (i >= n) return;
    float inv[9], det;
    inv3x3(cell, inv, &det);
    float wgt[3][4], dwg[3][4];
    int idx[3][4];
    atom_setup(pos, inv, i, wgt, dwg, idx);
    float acc0 = 0.0f, acc1 = 0.0f, acc2 = 0.0f;
#pragma unroll
    for (int j0 = 0; j0 < 4; j0++) {
        int r0 = idx[0][j0] << 14;
        float wx = wgt[0][j0], dx = dwg[0][j0];
#pragma unroll
        for (int j1 = 0; j1 < 4; j1++) {
            int r1 = r0 + (idx[1][j1] << 7);
            float wy = wgt[1][j1], dy = dwg[1][j1];
            float c00 = wx * wy;   // for acc2 (dwz)
            float c01 = wx * dy;   // for acc1
            float c02 = dx * wy;   // for acc0
#pragma unroll
            for (int j2 = 0; j2 < 4; j2++) {
                float phi = C[r1 + idx[2][j2]].x;
                float wz = wgt[2][j2], dz = dwg[2][j2];
                acc0 += phi * c02 * wz;
                acc1 += phi * c01 * wz;
                acc2 += phi * c00 * dz;
            }
        }
    }
    float qi = chg[i];
    // dE/dr_m = q * 2c * K * sum_d acc_d * cellinv[m][d];  F = -dE/dr
    float c = KE_F * TWO_PI_F / det;
    float fac = -2.0f * c * qi * (float)KDIM;
    float F0 = fac * (acc0 * inv[0] + acc1 * inv[1] + acc2 * inv[2]);
    float F1 = fac * (acc0 * inv[3] + acc1 * inv[4] + acc2 * inv[5]);
    float F2 = fac * (acc0 * inv[6] + acc1 * inv[7] + acc2 * inv[8]);
    out[1 + 3 * i + 0] = F0;
    out[1 + 3 * i + 1] = F1;
    out[1 + 3 * i + 2] = F2;
}

extern "C" void kernel_launch(void* const* d_in, const int* in_sizes, int n_in,
                              void* d_out, int out_size, void* d_ws, size_t ws_size,
                              hipStream_t stream) {
    const float* pos = (const float*)d_in[0];
    const float* chg = (const float*)d_in[1];
    const float* cell = (const float*)d_in[2];
    float* out = (float*)d_out;
    int n = in_sizes[1];

    float2* C = (float2*)d_ws;
    double* esums = (double*)((char*)d_ws + (size_t)NTOT * sizeof(float2));

    hipMemsetAsync(d_ws, 0, (size_t)NTOT * sizeof(float2) + 2 * sizeof(double), stream);

    int nb = (n + 255) / 256;
    spread_kernel<<<nb, 256, 0, stream>>>(pos, chg, cell, C, esums, n);

    // forward FFT (sign = -1)
    fft_line_z<<<2048, 512, 0, stream>>>(C, -1.0f);
    fft_line_t<<<2048, 512, 0, stream>>>(C, KDIM, KDIM * KDIM, -1.0f);  // y dim
    fft_line_t<<<2048, 512, 0, stream>>>(C, KDIM * KDIM, KDIM, -1.0f);  // x dim

    scale_kernel<<<NTOT / 256, 256, 0, stream>>>(C, cell, esums);

    // unnormalized inverse FFT (sign = +1)
    fft_line_z<<<2048, 512, 0, stream>>>(C, 1.0f);
    fft_line_t<<<2048, 512, 0, stream>>>(C, KDIM, KDIM * KDIM, 1.0f);
    fft_line_t<<<2048, 512, 0, stream>>>(C, KDIM * KDIM, KDIM, 1.0f);

    finalize_kernel<<<1, 1, 0, stream>>>(esums, cell, out);
    gather_kernel<<<nb, 256, 0, stream>>>(pos, chg, cell, C, out, n);
}

// Round 2
// 419.559 us; speedup vs baseline: 2.1817x; 2.1817x over previous
//
#include <hip/hip_runtime.h>

#define KDIM 128
#define NTOT (KDIM * KDIM * KDIM)
#define BPD 16          // bins per dim
#define NBINS (BPD * BPD * BPD)
#define TILE_D 11       // 8 + 3 overlap
#define TILE_N (TILE_D * TILE_D * TILE_D)

static constexpr float PI_F = 3.14159265358979323846f;
static constexpr float TWO_PI_F = 6.28318530717958647692f;
static constexpr float KE_F = 14.3996f;
static constexpr float ALPHA_F = 0.35f;

__device__ __forceinline__ int brev7(int i) { return (int)(__brev((unsigned)i) >> 25); }

__device__ __forceinline__ void inv3x3(const float* c, float* inv, float* adet) {
    float a00 = c[0], a01 = c[1], a02 = c[2];
    float a10 = c[3], a11 = c[4], a12 = c[5];
    float a20 = c[6], a21 = c[7], a22 = c[8];
    float det = a00 * (a11 * a22 - a12 * a21) - a01 * (a10 * a22 - a12 * a20) +
                a02 * (a10 * a21 - a11 * a20);
    float id = 1.0f / det;
    inv[0] = (a11 * a22 - a12 * a21) * id;
    inv[1] = (a02 * a21 - a01 * a22) * id;
    inv[2] = (a01 * a12 - a02 * a11) * id;
    inv[3] = (a12 * a20 - a10 * a22) * id;
    inv[4] = (a00 * a22 - a02 * a20) * id;
    inv[5] = (a02 * a10 - a00 * a12) * id;
    inv[6] = (a10 * a21 - a11 * a20) * id;
    inv[7] = (a01 * a20 - a00 * a21) * id;
    inv[8] = (a00 * a11 - a01 * a10) * id;
    *adet = fabsf(det);
}

// Cardinal B-spline M_4 weights at f in [0,1) (leftmost node first) + d/du.
__device__ __forceinline__ void bspline4(float f, float* w, float* dw) {
    float f2 = f * f, f3 = f2 * f;
    float omf = 1.0f - f;
    w[0] = omf * omf * omf * (1.0f / 6.0f);
    w[1] = (3.0f * f3 - 6.0f * f2 + 4.0f) * (1.0f / 6.0f);
    w[2] = (-3.0f * f3 + 3.0f * f2 + 3.0f * f + 1.0f) * (1.0f / 6.0f);
    w[3] = f3 * (1.0f / 6.0f);
    dw[0] = -0.5f * omf * omf;
    dw[1] = 1.5f * f2 - 2.0f * f;
    dw[2] = -1.5f * f2 + f + 0.5f;
    dw[3] = 0.5f * f2;
}

// frac -> per-dim base cell (0..127) and fractional part
__device__ __forceinline__ void atom_base(const float* __restrict__ pos, const float* inv,
                                          int i, int base[3], float fpart[3]) {
    float p0 = pos[3 * i], p1 = pos[3 * i + 1], p2 = pos[3 * i + 2];
#pragma unroll
    for (int d = 0; d < 3; d++) {
        float fr = p0 * inv[d] + p1 * inv[3 + d] + p2 * inv[6 + d];
        fr -= floorf(fr);
        float u = fr * (float)KDIM;
        float bs = floorf(u);
        fpart[d] = u - bs;
        int b = (int)bs;
        base[d] = b & (KDIM - 1);
    }
}

__device__ __forceinline__ void atom_setup(const float* __restrict__ pos, const float* inv,
                                           int i, float wgt[3][4], float dwg[3][4],
                                           int idx[3][4]) {
    int base[3];
    float fp[3];
    atom_base(pos, inv, i, base, fp);
#pragma unroll
    for (int d = 0; d < 3; d++) {
        bspline4(fp[d], wgt[d], dwg[d]);
#pragma unroll
        for (int j = 0; j < 4; j++) idx[d][j] = (base[d] - 3 + j + KDIM) & (KDIM - 1);
    }
}

// ---------------- binning: histogram + sum(q^2) ----------------
__global__ __launch_bounds__(256) void hist_kernel(const float* __restrict__ pos,
                                                   const float* __restrict__ chg,
                                                   const float* __restrict__ cell,
                                                   int* __restrict__ counts,
                                                   double* __restrict__ esums, int n) {
    int i = blockIdx.x * blockDim.x + threadIdx.x;
    float q2 = 0.0f;
    if (i < n) {
        float inv[9], det;
        inv3x3(cell, inv, &det);
        int base[3];
        float fp[3];
        atom_base(pos, inv, i, base, fp);
        int bid = ((base[0] >> 3) << 8) | ((base[1] >> 3) << 4) | (base[2] >> 3);
        atomicAdd(&counts[bid], 1);
        float qi = chg[i];
        q2 = qi * qi;
    }
#pragma unroll
    for (int off = 32; off; off >>= 1) q2 += __shfl_down(q2, off);
    if ((threadIdx.x & 63) == 0) atomicAdd(&esums[1], (double)q2);
}

// single-block exclusive scan over NBINS counts -> starts[NBINS+1]
__global__ __launch_bounds__(256) void scan_kernel(const int* __restrict__ counts,
                                                   int* __restrict__ starts) {
    __shared__ int part[256];
    int tid = threadIdx.x;
    int local[NBINS / 256];
    int sum = 0;
#pragma unroll
    for (int k = 0; k < NBINS / 256; k++) {
        local[k] = counts[tid * (NBINS / 256) + k];
        sum += local[k];
    }
    part[tid] = sum;
    __syncthreads();
    if (tid == 0) {
        int acc = 0;
        for (int i = 0; i < 256; i++) {
            int t = part[i];
            part[i] = acc;
            acc += t;
        }
        starts[NBINS] = acc;
    }
    __syncthreads();
    int acc = part[tid];
#pragma unroll
    for (int k = 0; k < NBINS / 256; k++) {
        starts[tid * (NBINS / 256) + k] = acc;
        acc += local[k];
    }
}

__global__ __launch_bounds__(256) void scatter_kernel(const float* __restrict__ pos,
                                                      const float* __restrict__ cell,
                                                      const int* __restrict__ starts,
                                                      int* __restrict__ cursor,
                                                      int* __restrict__ binatoms, int n) {
    int i = blockIdx.x * blockDim.x + threadIdx.x;
    if (i >= n) return;
    float inv[9], det;
    inv3x3(cell, inv, &det);
    int base[3];
    float fp[3];
    atom_base(pos, inv, i, base, fp);
    int bid = ((base[0] >> 3) << 8) | ((base[1] >> 3) << 4) | (base[2] >> 3);
    int slot = atomicAdd(&cursor[bid], 1);
    binatoms[starts[bid] + slot] = i;
}

// ---------------- binned LDS-privatized spreading ----------------
__global__ __launch_bounds__(256) void spread_bins_kernel(
    const float* __restrict__ pos, const float* __restrict__ chg,
    const float* __restrict__ cell, const int* __restrict__ starts,
    const int* __restrict__ binatoms, float2* __restrict__ C) {
    __shared__ float tile[TILE_N];
    __shared__ float awx[64][4], awy[64][4], awz[64][4];
    __shared__ int aloc[64];
    int tid = threadIdx.x;
    int bid = blockIdx.x;
    int bx = bid >> 8, by = (bid >> 4) & 15, bz = bid & 15;
    for (int i = tid; i < TILE_N; i += 256) tile[i] = 0.0f;
    float inv[9], det;
    inv3x3(cell, inv, &det);
    int s = starts[bid], e = starts[bid + 1];
    for (int c0 = s; c0 < e; c0 += 64) {
        int cnt = min(64, e - c0);
        if (tid < cnt) {
            int a = binatoms[c0 + tid];
            int base[3];
            float fp[3];
            atom_base(pos, inv, a, base, fp);
            float w[4], dw[4];
            float qi = chg[a];
            bspline4(fp[0], w, dw);
#pragma unroll
            for (int j = 0; j < 4; j++) awx[tid][j] = qi * w[j];
            bspline4(fp[1], w, dw);
#pragma unroll
            for (int j = 0; j < 4; j++) awy[tid][j] = w[j];
            bspline4(fp[2], w, dw);
#pragma unroll
            for (int j = 0; j < 4; j++) awz[tid][j] = w[j];
            aloc[tid] = (base[0] - (bx << 3)) | ((base[1] - (by << 3)) << 4) |
                        ((base[2] - (bz << 3)) << 8);
        }
        __syncthreads();
        int items = cnt << 4;
        for (int it = tid; it < items; it += 256) {
            int a = it >> 4, r = it & 15, j0 = r >> 2, j1 = r & 3;
            int lc = aloc[a];
            int lx = (lc & 15) + j0;
            int ly = ((lc >> 4) & 15) + j1;
            int lz = lc >> 8;
            float val = awx[a][j0] * awy[a][j1];
            int tb = (lx * TILE_D + ly) * TILE_D + lz;
#pragma unroll
            for (int j2 = 0; j2 < 4; j2++) atomicAdd(&tile[tb + j2], val * awz[a][j2]);
        }
        __syncthreads();
    }
    int gx0 = (bx << 3) - 3, gy0 = (by << 3) - 3, gz0 = (bz << 3) - 3;
    for (int i = tid; i < TILE_N; i += 256) {
        float v = tile[i];
        if (v != 0.0f) {
            int lx = i / (TILE_D * TILE_D);
            int r2 = i - lx * (TILE_D * TILE_D);
            int ly = r2 / TILE_D;
            int lz = r2 - ly * TILE_D;
            int gx = (gx0 + lx) & (KDIM - 1);
            int gy = (gy0 + ly) & (KDIM - 1);
            int gz = (gz0 + lz) & (KDIM - 1);
            atomicAdd(&C[(gx << 14) + (gy << 7) + gz].x, v);
        }
    }
}

// ---------------- 128-point FFT on an LDS line (one wave, lanes l=0..63) ----------------
__device__ __forceinline__ void fft128(float2* b, int st, int off, int l, float sign) {
    int i0 = brev7(l), i1 = brev7(l + 64);
    float2 r0 = b[i0 * st + off];
    float2 r1 = b[i1 * st + off];
    __syncthreads();
    b[l * st + off] = r0;
    b[(l + 64) * st + off] = r1;
    __syncthreads();
#pragma unroll
    for (int m = 1; m < 128; m <<= 1) {
        int pos = l & (m - 1);
        int bi = ((l & ~(m - 1)) << 1) | pos;
        float ang = sign * (PI_F / (float)m) * (float)pos;
        float sn, cs;
        __sincosf(ang, &sn, &cs);
        float2 E = b[bi * st + off];
        float2 O = b[(bi + m) * st + off];
        float2 t = make_float2(O.x * cs - O.y * sn, O.x * sn + O.y * cs);
        b[bi * st + off] = make_float2(E.x + t.x, E.y + t.y);
        b[(bi + m) * st + off] = make_float2(E.x - t.x, E.y - t.y);
        __syncthreads();
    }
}

// FFT along z (contiguous lines). 8 lines per block, one wave each.
__global__ __launch_bounds__(512) void fft_line_z(float2* __restrict__ C, float sign) {
    __shared__ float2 lds[8 * 128];
    int w = threadIdx.x >> 6, l = threadIdx.x & 63;
    int line = (blockIdx.x << 3) + w;
    float2* L = lds + (w << 7);
    int base = line << 7;
    L[l] = C[base + l];
    L[l + 64] = C[base + l + 64];
    __syncthreads();
    fft128(L, 1, 0, l, sign);
    C[base + l] = L[l];
    C[base + l + 64] = L[l + 64];
}

// FFT along a strided dim. Block handles 8 lines sharing 8 consecutive z.
__global__ __launch_bounds__(512) void fft_line_t(float2* __restrict__ C, int LS, int OS,
                                                  float sign) {
    __shared__ float2 lds[128 * 9];
    int tid = threadIdx.x;
    int p = blockIdx.x >> 4;
    int z0 = (blockIdx.x & 15) << 3;
    int base = p * OS + z0;
#pragma unroll
    for (int kk = 0; kk < 2; kk++) {
        int e = tid + (kk << 9);
        int ll = e >> 3, zt = e & 7;
        lds[ll * 9 + zt] = C[base + ll * LS + zt];
    }
    __syncthreads();
    fft128(lds, 9, tid >> 6, tid & 63, sign);
#pragma unroll
    for (int kk = 0; kk < 2; kk++) {
        int e = tid + (kk << 9);
        int ll = e >> 3, zt = e & 7;
        C[base + ll * LS + zt] = lds[ll * 9 + zt];
    }
}

// ---------------- reciprocal-space scale + energy reduction ----------------
__device__ __forceinline__ float bmod2f(int x) {
    float th = (TWO_PI_F / (float)KDIM) * (float)x;
    float s1, c1, s2, c2;
    __sincosf(th, &s1, &c1);
    __sincosf(th + th, &s2, &c2);
    float dr = 0.16666667f + 0.66666667f * c1 + 0.16666667f * c2;
    float di = 0.66666667f * s1 + 0.16666667f * s2;
    float d2 = dr * dr + di * di;
    return 1.0f / fmaxf(d2, 1e-12f);
}

__global__ __launch_bounds__(256) void scale_kernel(float2* __restrict__ C,
                                                    const float* __restrict__ cell,
                                                    double* __restrict__ esums) {
    __shared__ float red[4];
    int idx = blockIdx.x * 256 + threadIdx.x;
    float inv[9], det;
    inv3x3(cell, inv, &det);
    int x = idx >> 14, y = (idx >> 7) & 127, z = idx & 127;
    float mx = (float)(x < 64 ? x : x - 128);
    float my = (float)(y < 64 ? y : y - 128);
    float mz = (float)(z < 64 ? z : z - 128);
    float kx = TWO_PI_F * (mx * inv[0] + my * inv[1] + mz * inv[2]);
    float ky = TWO_PI_F * (mx * inv[3] + my * inv[4] + mz * inv[5]);
    float kz = TWO_PI_F * (mx * inv[6] + my * inv[7] + mz * inv[8]);
    float k2 = kx * kx + ky * ky + kz * kz;
    float A = 0.0f;
    if (k2 > 0.0f) {
        A = __expf(-k2 / (4.0f * ALPHA_F * ALPHA_F)) / k2;
        A *= bmod2f(x) * bmod2f(y) * bmod2f(z);
    }
    float2 s = C[idx];
    float contrib = A * (s.x * s.x + s.y * s.y);
    C[idx] = make_float2(s.x * A, s.y * A);
#pragma unroll
    for (int off = 32; off; off >>= 1) contrib += __shfl_down(contrib, off);
    int w = threadIdx.x >> 6;
    if ((threadIdx.x & 63) == 0) red[w] = contrib;
    __syncthreads();
    if (threadIdx.x == 0) {
        float v = red[0] + red[1] + red[2] + red[3];
        atomicAdd(&esums[0], (double)v);
    }
}

// ---------------- energy finalize ----------------
__global__ void finalize_kernel(const double* __restrict__ esums,
                                const float* __restrict__ cell, float* __restrict__ out) {
    float inv[9], det;
    inv3x3(cell, inv, &det);
    double c = (double)KE_F * 2.0 * 3.14159265358979323846 / (double)det;
    double e = c * esums[0] -
               (double)KE_F * (double)ALPHA_F / 1.7724538509055160273 * esums[1];
    out[0] = (float)e;
}

// ---------------- force gather ----------------
__global__ __launch_bounds__(256) void gather_kernel(const float* __restrict__ pos,
                                                     const float* __restrict__ chg,
                                                     const float* __restrict__ cell,
                                                     const float2* __restrict__ C,
                                                     float* __restrict__ out, int n) {
    int i = blockIdx.x * blockDim.x + threadIdx.x;
    if (i >= n) return;
    float inv[9], det;
    inv3x3(cell, inv, &det);
    float wgt[3][4], dwg[3][4];
    int idx[3][4];
    atom_setup(pos, inv, i, wgt, dwg, idx);
    float acc0 = 0.0f, acc1 = 0.0f, acc2 = 0.0f;
#pragma unroll
    for (int j0 = 0; j0 < 4; j0++) {
        int r0 = idx[0][j0] << 14;
        float wx = wgt[0][j0], dx = dwg[0][j0];
#pragma unroll
        for (int j1 = 0; j1 < 4; j1++) {
            int r1 = r0 + (idx[1][j1] << 7);
            float wy = wgt[1][j1], dy = dwg[1][j1];
            float c00 = wx * wy;
            float c01 = wx * dy;
            float c02 = dx * wy;
#pragma unroll
            for (int j2 = 0; j2 < 4; j2++) {
                float phi = C[r1 + idx[2][j2]].x;
                float wz = wgt[2][j2], dz = dwg[2][j2];
                acc0 += phi * c02 * wz;
                acc1 += phi * c01 * wz;
                acc2 += phi * c00 * dz;
            }
        }
    }
    float qi = chg[i];
    float c = KE_F * TWO_PI_F / det;
    float fac = -2.0f * c * qi * (float)KDIM;
    float F0 = fac * (acc0 * inv[0] + acc1 * inv[1] + acc2 * inv[2]);
    float F1 = fac * (acc0 * inv[3] + acc1 * inv[4] + acc2 * inv[5]);
    float F2 = fac * (acc0 * inv[6] + acc1 * inv[7] + acc2 * inv[8]);
    out[1 + 3 * i + 0] = F0;
    out[1 + 3 * i + 1] = F1;
    out[1 + 3 * i + 2] = F2;
}

extern "C" void kernel_launch(void* const* d_in, const int* in_sizes, int n_in,
                              void* d_out, int out_size, void* d_ws, size_t ws_size,
                              hipStream_t stream) {
    const float* pos = (const float*)d_in[0];
    const float* chg = (const float*)d_in[1];
    const float* cell = (const float*)d_in[2];
    float* out = (float*)d_out;
    int n = in_sizes[1];

    char* w = (char*)d_ws;
    float2* C = (float2*)w;                       // 16 MB
    size_t off = (size_t)NTOT * sizeof(float2);
    double* esums = (double*)(w + off);           // 2 doubles
    off += 2 * sizeof(double);
    int* counts = (int*)(w + off);                // NBINS
    off += NBINS * sizeof(int);
    int* cursor = (int*)(w + off);                // NBINS
    off += NBINS * sizeof(int);
    size_t zero_bytes = off;                      // everything above gets zeroed
    int* starts = (int*)(w + off);                // NBINS+1 (written by scan)
    off += (NBINS + 1) * sizeof(int);
    int* binatoms = (int*)(w + off);              // n ints

    hipMemsetAsync(d_ws, 0, zero_bytes, stream);

    int nb = (n + 255) / 256;
    hist_kernel<<<nb, 256, 0, stream>>>(pos, chg, cell, counts, esums, n);
    scan_kernel<<<1, 256, 0, stream>>>(counts, starts);
    scatter_kernel<<<nb, 256, 0, stream>>>(pos, cell, starts, cursor, binatoms, n);
    spread_bins_kernel<<<NBINS, 256, 0, stream>>>(pos, chg, cell, starts, binatoms, C);

    // forward FFT (sign = -1)
    fft_line_z<<<2048, 512, 0, stream>>>(C, -1.0f);
    fft_line_t<<<2048, 512, 0, stream>>>(C, KDIM, KDIM * KDIM, -1.0f);  // y dim
    fft_line_t<<<2048, 512, 0, stream>>>(C, KDIM * KDIM, KDIM, -1.0f);  // x dim

    scale_kernel<<<NTOT / 256, 256, 0, stream>>>(C, cell, esums);

    // unnormalized inverse FFT (sign = +1)
    fft_line_z<<<2048, 512, 0, stream>>>(C, 1.0f);
    fft_line_t<<<2048, 512, 0, stream>>>(C, KDIM, KDIM * KDIM, 1.0f);
    fft_line_t<<<2048, 512, 0, stream>>>(C, KDIM * KDIM, KDIM, 1.0f);

    finalize_kernel<<<1, 1, 0, stream>>>(esums, cell, out);
    gather_kernel<<<nb, 256, 0, stream>>>(pos, chg, cell, C, out, n);
}

// Round 3
// 297.695 us; speedup vs baseline: 3.0748x; 1.4094x over previous
//
#include <hip/hip_runtime.h>

#define KDIM 128
#define NTOT (KDIM * KDIM * KDIM)
#define BPD 16          // bins per dim
#define NBINS (BPD * BPD * BPD)
#define TILE_D 11       // 8 + 3 overlap
#define TILE_N (TILE_D * TILE_D * TILE_D)
#define NSCALE_BLK (NTOT / 256)

static constexpr float PI_F = 3.14159265358979323846f;
static constexpr float TWO_PI_F = 6.28318530717958647692f;
static constexpr float KE_F = 14.3996f;
static constexpr float ALPHA_F = 0.35f;

__device__ __forceinline__ int brev7(int i) { return (int)(__brev((unsigned)i) >> 25); }

__device__ __forceinline__ void inv3x3(const float* c, float* inv, float* adet) {
    float a00 = c[0], a01 = c[1], a02 = c[2];
    float a10 = c[3], a11 = c[4], a12 = c[5];
    float a20 = c[6], a21 = c[7], a22 = c[8];
    float det = a00 * (a11 * a22 - a12 * a21) - a01 * (a10 * a22 - a12 * a20) +
                a02 * (a10 * a21 - a11 * a20);
    float id = 1.0f / det;
    inv[0] = (a11 * a22 - a12 * a21) * id;
    inv[1] = (a02 * a21 - a01 * a22) * id;
    inv[2] = (a01 * a12 - a02 * a11) * id;
    inv[3] = (a12 * a20 - a10 * a22) * id;
    inv[4] = (a00 * a22 - a02 * a20) * id;
    inv[5] = (a02 * a10 - a00 * a12) * id;
    inv[6] = (a10 * a21 - a11 * a20) * id;
    inv[7] = (a01 * a20 - a00 * a21) * id;
    inv[8] = (a00 * a11 - a01 * a10) * id;
    *adet = fabsf(det);
}

// Cardinal B-spline M_4 weights at f in [0,1) (leftmost node first) + d/du.
__device__ __forceinline__ void bspline4(float f, float* w, float* dw) {
    float f2 = f * f, f3 = f2 * f;
    float omf = 1.0f - f;
    w[0] = omf * omf * omf * (1.0f / 6.0f);
    w[1] = (3.0f * f3 - 6.0f * f2 + 4.0f) * (1.0f / 6.0f);
    w[2] = (-3.0f * f3 + 3.0f * f2 + 3.0f * f + 1.0f) * (1.0f / 6.0f);
    w[3] = f3 * (1.0f / 6.0f);
    dw[0] = -0.5f * omf * omf;
    dw[1] = 1.5f * f2 - 2.0f * f;
    dw[2] = -1.5f * f2 + f + 0.5f;
    dw[3] = 0.5f * f2;
}

__device__ __forceinline__ void atom_base(const float* __restrict__ pos, const float* inv,
                                          int i, int base[3], float fpart[3]) {
    float p0 = pos[3 * i], p1 = pos[3 * i + 1], p2 = pos[3 * i + 2];
#pragma unroll
    for (int d = 0; d < 3; d++) {
        float fr = p0 * inv[d] + p1 * inv[3 + d] + p2 * inv[6 + d];
        fr -= floorf(fr);
        float u = fr * (float)KDIM;
        float bs = floorf(u);
        fpart[d] = u - bs;
        int b = (int)bs;
        base[d] = b & (KDIM - 1);
    }
}

__device__ __forceinline__ void atom_setup(const float* __restrict__ pos, const float* inv,
                                           int i, float wgt[3][4], float dwg[3][4],
                                           int idx[3][4]) {
    int base[3];
    float fp[3];
    atom_base(pos, inv, i, base, fp);
#pragma unroll
    for (int d = 0; d < 3; d++) {
        bspline4(fp[d], wgt[d], dwg[d]);
#pragma unroll
        for (int j = 0; j < 4; j++) idx[d][j] = (base[d] - 3 + j + KDIM) & (KDIM - 1);
    }
}

// ---------------- binning: histogram + per-block sum(q^2) ----------------
__global__ __launch_bounds__(256) void hist_kernel(const float* __restrict__ pos,
                                                   const float* __restrict__ chg,
                                                   const float* __restrict__ cell,
                                                   int* __restrict__ counts,
                                                   float* __restrict__ q2_part, int n) {
    __shared__ float hred[4];
    int i = blockIdx.x * blockDim.x + threadIdx.x;
    float q2 = 0.0f;
    if (i < n) {
        float inv[9], det;
        inv3x3(cell, inv, &det);
        int base[3];
        float fp[3];
        atom_base(pos, inv, i, base, fp);
        int bid = ((base[0] >> 3) << 8) | ((base[1] >> 3) << 4) | (base[2] >> 3);
        atomicAdd(&counts[bid], 1);
        float qi = chg[i];
        q2 = qi * qi;
    }
#pragma unroll
    for (int off = 32; off; off >>= 1) q2 += __shfl_down(q2, off);
    if ((threadIdx.x & 63) == 0) hred[threadIdx.x >> 6] = q2;
    __syncthreads();
    if (threadIdx.x == 0) q2_part[blockIdx.x] = hred[0] + hred[1] + hred[2] + hred[3];
}

// single-block exclusive scan over NBINS counts -> starts[NBINS+1]
__global__ __launch_bounds__(256) void scan_kernel(const int* __restrict__ counts,
                                                   int* __restrict__ starts) {
    __shared__ int part[256];
    int tid = threadIdx.x;
    int local[NBINS / 256];
    int sum = 0;
#pragma unroll
    for (int k = 0; k < NBINS / 256; k++) {
        local[k] = counts[tid * (NBINS / 256) + k];
        sum += local[k];
    }
    part[tid] = sum;
    __syncthreads();
    if (tid == 0) {
        int acc = 0;
        for (int i = 0; i < 256; i++) {
            int t = part[i];
            part[i] = acc;
            acc += t;
        }
        starts[NBINS] = acc;
    }
    __syncthreads();
    int acc = part[tid];
#pragma unroll
    for (int k = 0; k < NBINS / 256; k++) {
        starts[tid * (NBINS / 256) + k] = acc;
        acc += local[k];
    }
}

__global__ __launch_bounds__(256) void scatter_kernel(const float* __restrict__ pos,
                                                      const float* __restrict__ cell,
                                                      const int* __restrict__ starts,
                                                      int* __restrict__ cursor,
                                                      int* __restrict__ binatoms, int n) {
    int i = blockIdx.x * blockDim.x + threadIdx.x;
    if (i >= n) return;
    float inv[9], det;
    inv3x3(cell, inv, &det);
    int base[3];
    float fp[3];
    atom_base(pos, inv, i, base, fp);
    int bid = ((base[0] >> 3) << 8) | ((base[1] >> 3) << 4) | (base[2] >> 3);
    int slot = atomicAdd(&cursor[bid], 1);
    binatoms[starts[bid] + slot] = i;
}

// ---------------- binned LDS-privatized spreading ----------------
__global__ __launch_bounds__(256) void spread_bins_kernel(
    const float* __restrict__ pos, const float* __restrict__ chg,
    const float* __restrict__ cell, const int* __restrict__ starts,
    const int* __restrict__ binatoms, float2* __restrict__ C) {
    __shared__ float tile[TILE_N];
    __shared__ float awx[64][4], awy[64][4], awz[64][4];
    __shared__ int aloc[64];
    int tid = threadIdx.x;
    int bid = blockIdx.x;
    int bx = bid >> 8, by = (bid >> 4) & 15, bz = bid & 15;
    for (int i = tid; i < TILE_N; i += 256) tile[i] = 0.0f;
    float inv[9], det;
    inv3x3(cell, inv, &det);
    int s = starts[bid], e = starts[bid + 1];
    for (int c0 = s; c0 < e; c0 += 64) {
        int cnt = min(64, e - c0);
        if (tid < cnt) {
            int a = binatoms[c0 + tid];
            int base[3];
            float fp[3];
            atom_base(pos, inv, a, base, fp);
            float w[4], dw[4];
            float qi = chg[a];
            bspline4(fp[0], w, dw);
#pragma unroll
            for (int j = 0; j < 4; j++) awx[tid][j] = qi * w[j];
            bspline4(fp[1], w, dw);
#pragma unroll
            for (int j = 0; j < 4; j++) awy[tid][j] = w[j];
            bspline4(fp[2], w, dw);
#pragma unroll
            for (int j = 0; j < 4; j++) awz[tid][j] = w[j];
            aloc[tid] = (base[0] - (bx << 3)) | ((base[1] - (by << 3)) << 4) |
                        ((base[2] - (bz << 3)) << 8);
        }
        __syncthreads();
        int items = cnt << 4;
        for (int it = tid; it < items; it += 256) {
            int a = it >> 4, r = it & 15, j0 = r >> 2, j1 = r & 3;
            int lc = aloc[a];
            int lx = (lc & 15) + j0;
            int ly = ((lc >> 4) & 15) + j1;
            int lz = lc >> 8;
            float val = awx[a][j0] * awy[a][j1];
            int tb = (lx * TILE_D + ly) * TILE_D + lz;
#pragma unroll
            for (int j2 = 0; j2 < 4; j2++) atomicAdd(&tile[tb + j2], val * awz[a][j2]);
        }
        __syncthreads();
    }
    int gx0 = (bx << 3) - 3, gy0 = (by << 3) - 3, gz0 = (bz << 3) - 3;
    for (int i = tid; i < TILE_N; i += 256) {
        float v = tile[i];
        if (v != 0.0f) {
            int lx = i / (TILE_D * TILE_D);
            int r2 = i - lx * (TILE_D * TILE_D);
            int ly = r2 / TILE_D;
            int lz = r2 - ly * TILE_D;
            int gx = (gx0 + lx) & (KDIM - 1);
            int gy = (gy0 + ly) & (KDIM - 1);
            int gz = (gz0 + lz) & (KDIM - 1);
            atomicAdd(&C[(gx << 14) + (gy << 7) + gz].x, v);
        }
    }
}

// ---------------- wave-level 128-point FFT: 2 complex per lane, shuffles only --------
__device__ __forceinline__ float2 cmul(float2 a, float cs, float sn) {
    return make_float2(a.x * cs - a.y * sn, a.x * sn + a.y * cs);
}

// Input: v0 = element brev-loaded slot l, v1 = slot l+64 (l = lane 0..63).
// Output: natural order, v0 = element l, v1 = element l+64.
__device__ __forceinline__ void wave_fft128(float2& v0, float2& v1, int l, float sign) {
#pragma unroll
    for (int m = 1; m <= 32; m <<= 1) {
        float2 p0, p1;
        p0.x = __shfl_xor(v0.x, m);
        p0.y = __shfl_xor(v0.y, m);
        p1.x = __shfl_xor(v1.x, m);
        p1.y = __shfl_xor(v1.y, m);
        float ang = sign * (PI_F / (float)m) * (float)(l & (m - 1));
        float sn, cs;
        __sincosf(ang, &sn, &cs);
        bool hi = (l & m) != 0;
        float2 o0 = hi ? v0 : p0, e0 = hi ? p0 : v0;
        float2 o1 = hi ? v1 : p1, e1 = hi ? p1 : v1;
        float2 t0 = cmul(o0, cs, sn);
        float2 t1 = cmul(o1, cs, sn);
        float s = hi ? -1.0f : 1.0f;
        v0 = make_float2(e0.x + s * t0.x, e0.y + s * t0.y);
        v1 = make_float2(e1.x + s * t1.x, e1.y + s * t1.y);
    }
    // final stage m=64: partner held in-lane
    float ang = sign * (PI_F / 64.0f) * (float)l;
    float sn, cs;
    __sincosf(ang, &sn, &cs);
    float2 t = cmul(v1, cs, sn);
    float2 e = v0;
    v0 = make_float2(e.x + t.x, e.y + t.y);
    v1 = make_float2(e.x - t.x, e.y - t.y);
}

// FFT along z (contiguous lines). 8 lines per block, one wave each. No LDS.
__global__ __launch_bounds__(512) void fft_z(float2* __restrict__ C, float sign) {
    int w = threadIdx.x >> 6, l = threadIdx.x & 63;
    int line = (blockIdx.x << 3) + w;
    int base = line << 7;
    int r = brev7(l);  // even; brev7(l+64) = r+1
    float2 v0 = C[base + r];
    float2 v1 = C[base + r + 1];
    wave_fft128(v0, v1, l, sign);
    C[base + l] = v0;
    C[base + l + 64] = v1;
}

// FFT along a strided dim. Block: 8 lines sharing 8 consecutive z; LDS = transpose stage.
__global__ __launch_bounds__(512) void fft_t(float2* __restrict__ C, int LS, int OS,
                                             float sign) {
    __shared__ float2 lds[128 * 9];
    int tid = threadIdx.x;
    int p = blockIdx.x >> 4;
    int z0 = (blockIdx.x & 15) << 3;
    int base = p * OS + z0;
#pragma unroll
    for (int kk = 0; kk < 2; kk++) {
        int e = tid + (kk << 9);
        int ll = e >> 3, zt = e & 7;
        lds[ll * 9 + zt] = C[base + ll * LS + zt];
    }
    __syncthreads();
    int w = tid >> 6, l = tid & 63;
    int r = brev7(l);
    float2 v0 = lds[r * 9 + w];
    float2 v1 = lds[(r + 1) * 9 + w];
    wave_fft128(v0, v1, l, sign);
    // each wave reads/writes only its own column w -> no barrier needed in between
    lds[l * 9 + w] = v0;
    lds[(l + 64) * 9 + w] = v1;
    __syncthreads();
#pragma unroll
    for (int kk = 0; kk < 2; kk++) {
        int e = tid + (kk << 9);
        int ll = e >> 3, zt = e & 7;
        C[base + ll * LS + zt] = lds[ll * 9 + zt];
    }
}

// ---------------- reciprocal-space scale + per-block energy partial ----------------
__device__ __forceinline__ float bmod2f(int x) {
    float th = (TWO_PI_F / (float)KDIM) * (float)x;
    float s1, c1, s2, c2;
    __sincosf(th, &s1, &c1);
    __sincosf(th + th, &s2, &c2);
    float dr = 0.16666667f + 0.66666667f * c1 + 0.16666667f * c2;
    float di = 0.66666667f * s1 + 0.16666667f * s2;
    float d2 = dr * dr + di * di;
    return 1.0f / fmaxf(d2, 1e-12f);
}

__global__ __launch_bounds__(256) void scale_kernel(float2* __restrict__ C,
                                                    const float* __restrict__ cell,
                                                    float* __restrict__ scale_part) {
    __shared__ float red[4];
    int idx = blockIdx.x * 256 + threadIdx.x;
    float inv[9], det;
    inv3x3(cell, inv, &det);
    int x = idx >> 14, y = (idx >> 7) & 127, z = idx & 127;
    float mx = (float)(x < 64 ? x : x - 128);
    float my = (float)(y < 64 ? y : y - 128);
    float mz = (float)(z < 64 ? z : z - 128);
    float kx = TWO_PI_F * (mx * inv[0] + my * inv[1] + mz * inv[2]);
    float ky = TWO_PI_F * (mx * inv[3] + my * inv[4] + mz * inv[5]);
    float kz = TWO_PI_F * (mx * inv[6] + my * inv[7] + mz * inv[8]);
    float k2 = kx * kx + ky * ky + kz * kz;
    float A = 0.0f;
    if (k2 > 0.0f) {
        A = __expf(-k2 / (4.0f * ALPHA_F * ALPHA_F)) / k2;
        A *= bmod2f(x) * bmod2f(y) * bmod2f(z);
    }
    float2 s = C[idx];
    float contrib = A * (s.x * s.x + s.y * s.y);
    C[idx] = make_float2(s.x * A, s.y * A);
#pragma unroll
    for (int off = 32; off; off >>= 1) contrib += __shfl_down(contrib, off);
    int w = threadIdx.x >> 6;
    if ((threadIdx.x & 63) == 0) red[w] = contrib;
    __syncthreads();
    if (threadIdx.x == 0) scale_part[blockIdx.x] = red[0] + red[1] + red[2] + red[3];
}

// ---------------- energy finalize (reduce partial arrays in double) ----------------
__global__ __launch_bounds__(256) void finalize_kernel(const float* __restrict__ scale_part,
                                                       const float* __restrict__ q2_part,
                                                       int nq2,
                                                       const float* __restrict__ cell,
                                                       float* __restrict__ out) {
    __shared__ double sd[256];
    int tid = threadIdx.x;
    double es = 0.0;
    for (int i = tid; i < NSCALE_BLK; i += 256) es += (double)scale_part[i];
    double q2 = 0.0;
    for (int i = tid; i < nq2; i += 256) q2 += (double)q2_part[i];
    sd[tid] = es;
    __syncthreads();
    for (int s = 128; s; s >>= 1) {
        if (tid < s) sd[tid] += sd[tid + s];
        __syncthreads();
    }
    double esum = sd[0];
    __syncthreads();
    sd[tid] = q2;
    __syncthreads();
    for (int s = 128; s; s >>= 1) {
        if (tid < s) sd[tid] += sd[tid + s];
        __syncthreads();
    }
    if (tid == 0) {
        float inv[9], det;
        inv3x3(cell, inv, &det);
        double c = (double)KE_F * 2.0 * 3.14159265358979323846 / (double)det;
        double e = c * esum -
                   (double)KE_F * (double)ALPHA_F / 1.7724538509055160273 * sd[0];
        out[0] = (float)e;
    }
}

// ---------------- force gather ----------------
__global__ __launch_bounds__(256) void gather_kernel(const float* __restrict__ pos,
                                                     const float* __restrict__ chg,
                                                     const float* __restrict__ cell,
                                                     const float2* __restrict__ C,
                                                     float* __restrict__ out, int n) {
    int i = blockIdx.x * blockDim.x + threadIdx.x;
    if (i >= n) return;
    float inv[9], det;
    inv3x3(cell, inv, &det);
    float wgt[3][4], dwg[3][4];
    int idx[3][4];
    atom_setup(pos, inv, i, wgt, dwg, idx);
    float acc0 = 0.0f, acc1 = 0.0f, acc2 = 0.0f;
#pragma unroll
    for (int j0 = 0; j0 < 4; j0++) {
        int r0 = idx[0][j0] << 14;
        float wx = wgt[0][j0], dx = dwg[0][j0];
#pragma unroll
        for (int j1 = 0; j1 < 4; j1++) {
            int r1 = r0 + (idx[1][j1] << 7);
            float wy = wgt[1][j1], dy = dwg[1][j1];
            float c00 = wx * wy;
            float c01 = wx * dy;
            float c02 = dx * wy;
#pragma unroll
            for (int j2 = 0; j2 < 4; j2++) {
                float phi = C[r1 + idx[2][j2]].x;
                float wz = wgt[2][j2], dz = dwg[2][j2];
                acc0 += phi * c02 * wz;
                acc1 += phi * c01 * wz;
                acc2 += phi * c00 * dz;
            }
        }
    }
    float qi = chg[i];
    float c = KE_F * TWO_PI_F / det;
    float fac = -2.0f * c * qi * (float)KDIM;
    float F0 = fac * (acc0 * inv[0] + acc1 * inv[1] + acc2 * inv[2]);
    float F1 = fac * (acc0 * inv[3] + acc1 * inv[4] + acc2 * inv[5]);
    float F2 = fac * (acc0 * inv[6] + acc1 * inv[7] + acc2 * inv[8]);
    out[1 + 3 * i + 0] = F0;
    out[1 + 3 * i + 1] = F1;
    out[1 + 3 * i + 2] = F2;
}

extern "C" void kernel_launch(void* const* d_in, const int* in_sizes, int n_in,
                              void* d_out, int out_size, void* d_ws, size_t ws_size,
                              hipStream_t stream) {
    const float* pos = (const float*)d_in[0];
    const float* chg = (const float*)d_in[1];
    const float* cell = (const float*)d_in[2];
    float* out = (float*)d_out;
    int n = in_sizes[1];
    int nb = (n + 255) / 256;

    char* w = (char*)d_ws;
    float2* C = (float2*)w;                       // 16 MB (zeroed)
    size_t off = (size_t)NTOT * sizeof(float2);
    int* counts = (int*)(w + off);                // NBINS (zeroed)
    off += NBINS * sizeof(int);
    int* cursor = (int*)(w + off);                // NBINS (zeroed)
    off += NBINS * sizeof(int);
    size_t zero_bytes = off;
    int* starts = (int*)(w + off);                // NBINS+1
    off += (NBINS + 1) * sizeof(int);
    int* binatoms = (int*)(w + off);              // n
    off += (size_t)n * sizeof(int);
    float* scale_part = (float*)(w + off);        // NSCALE_BLK
    off += NSCALE_BLK * sizeof(float);
    float* q2_part = (float*)(w + off);           // nb

    hipMemsetAsync(d_ws, 0, zero_bytes, stream);

    hist_kernel<<<nb, 256, 0, stream>>>(pos, chg, cell, counts, q2_part, n);
    scan_kernel<<<1, 256, 0, stream>>>(counts, starts);
    scatter_kernel<<<nb, 256, 0, stream>>>(pos, cell, starts, cursor, binatoms, n);
    spread_bins_kernel<<<NBINS, 256, 0, stream>>>(pos, chg, cell, starts, binatoms, C);

    // forward FFT (sign = -1)
    fft_z<<<2048, 512, 0, stream>>>(C, -1.0f);
    fft_t<<<2048, 512, 0, stream>>>(C, KDIM, KDIM * KDIM, -1.0f);  // y dim
    fft_t<<<2048, 512, 0, stream>>>(C, KDIM * KDIM, KDIM, -1.0f);  // x dim

    scale_kernel<<<NSCALE_BLK, 256, 0, stream>>>(C, cell, scale_part);

    // unnormalized inverse FFT (sign = +1)
    fft_z<<<2048, 512, 0, stream>>>(C, 1.0f);
    fft_t<<<2048, 512, 0, stream>>>(C, KDIM, KDIM * KDIM, 1.0f);
    fft_t<<<2048, 512, 0, stream>>>(C, KDIM * KDIM, KDIM, 1.0f);

    finalize_kernel<<<1, 256, 0, stream>>>(scale_part, q2_part, nb, cell, out);
    gather_kernel<<<nb, 256, 0, stream>>>(pos, chg, cell, C, out, n);
}

// Round 4
// 275.716 us; speedup vs baseline: 3.3199x; 1.0797x over previous
//
#include <hip/hip_runtime.h>

#define KDIM 128
#define NTOT (KDIM * KDIM * KDIM)
#define BPD 16          // bins per dim
#define NBINS (BPD * BPD * BPD)
#define TILE_D 11       // 8 + 3 overlap
#define TILE_N (TILE_D * TILE_D * TILE_D)
#define TSTRIDE 1344    // padded tile stride (floats)
#define NSCALE_BLK 2048 // fused x-pass blocks

static constexpr float PI_F = 3.14159265358979323846f;
static constexpr float TWO_PI_F = 6.28318530717958647692f;
static constexpr float KE_F = 14.3996f;
static constexpr float ALPHA_F = 0.35f;

__device__ __forceinline__ int brev7(int i) { return (int)(__brev((unsigned)i) >> 25); }

__device__ __forceinline__ void inv3x3(const float* c, float* inv, float* adet) {
    float a00 = c[0], a01 = c[1], a02 = c[2];
    float a10 = c[3], a11 = c[4], a12 = c[5];
    float a20 = c[6], a21 = c[7], a22 = c[8];
    float det = a00 * (a11 * a22 - a12 * a21) - a01 * (a10 * a22 - a12 * a20) +
                a02 * (a10 * a21 - a11 * a20);
    float id = 1.0f / det;
    inv[0] = (a11 * a22 - a12 * a21) * id;
    inv[1] = (a02 * a21 - a01 * a22) * id;
    inv[2] = (a01 * a12 - a02 * a11) * id;
    inv[3] = (a12 * a20 - a10 * a22) * id;
    inv[4] = (a00 * a22 - a02 * a20) * id;
    inv[5] = (a02 * a10 - a00 * a12) * id;
    inv[6] = (a10 * a21 - a11 * a20) * id;
    inv[7] = (a01 * a20 - a00 * a21) * id;
    inv[8] = (a00 * a11 - a01 * a10) * id;
    *adet = fabsf(det);
}

__device__ __forceinline__ void bspline4(float f, float* w, float* dw) {
    float f2 = f * f, f3 = f2 * f;
    float omf = 1.0f - f;
    w[0] = omf * omf * omf * (1.0f / 6.0f);
    w[1] = (3.0f * f3 - 6.0f * f2 + 4.0f) * (1.0f / 6.0f);
    w[2] = (-3.0f * f3 + 3.0f * f2 + 3.0f * f + 1.0f) * (1.0f / 6.0f);
    w[3] = f3 * (1.0f / 6.0f);
    dw[0] = -0.5f * omf * omf;
    dw[1] = 1.5f * f2 - 2.0f * f;
    dw[2] = -1.5f * f2 + f + 0.5f;
    dw[3] = 0.5f * f2;
}

__device__ __forceinline__ void atom_base(const float* __restrict__ pos, const float* inv,
                                          int i, int base[3], float fpart[3]) {
    float p0 = pos[3 * i], p1 = pos[3 * i + 1], p2 = pos[3 * i + 2];
#pragma unroll
    for (int d = 0; d < 3; d++) {
        float fr = p0 * inv[d] + p1 * inv[3 + d] + p2 * inv[6 + d];
        fr -= floorf(fr);
        float u = fr * (float)KDIM;
        float bs = floorf(u);
        fpart[d] = u - bs;
        int b = (int)bs;
        base[d] = b & (KDIM - 1);
    }
}

__device__ __forceinline__ void atom_setup(const float* __restrict__ pos, const float* inv,
                                           int i, float wgt[3][4], float dwg[3][4],
                                           int idx[3][4]) {
    int base[3];
    float fp[3];
    atom_base(pos, inv, i, base, fp);
#pragma unroll
    for (int d = 0; d < 3; d++) {
        bspline4(fp[d], wgt[d], dwg[d]);
#pragma unroll
        for (int j = 0; j < 4; j++) idx[d][j] = (base[d] - 3 + j + KDIM) & (KDIM - 1);
    }
}

// ---------------- binning: histogram + per-block sum(q^2) ----------------
__global__ __launch_bounds__(256) void hist_kernel(const float* __restrict__ pos,
                                                   const float* __restrict__ chg,
                                                   const float* __restrict__ cell,
                                                   int* __restrict__ counts,
                                                   float* __restrict__ q2_part, int n) {
    __shared__ float hred[4];
    int i = blockIdx.x * blockDim.x + threadIdx.x;
    float q2 = 0.0f;
    if (i < n) {
        float inv[9], det;
        inv3x3(cell, inv, &det);
        int base[3];
        float fp[3];
        atom_base(pos, inv, i, base, fp);
        int bid = ((base[0] >> 3) << 8) | ((base[1] >> 3) << 4) | (base[2] >> 3);
        atomicAdd(&counts[bid], 1);
        float qi = chg[i];
        q2 = qi * qi;
    }
#pragma unroll
    for (int off = 32; off; off >>= 1) q2 += __shfl_down(q2, off);
    if ((threadIdx.x & 63) == 0) hred[threadIdx.x >> 6] = q2;
    __syncthreads();
    if (threadIdx.x == 0) q2_part[blockIdx.x] = hred[0] + hred[1] + hred[2] + hred[3];
}

__global__ __launch_bounds__(256) void scan_kernel(const int* __restrict__ counts,
                                                   int* __restrict__ starts) {
    __shared__ int part[256];
    int tid = threadIdx.x;
    int local[NBINS / 256];
    int sum = 0;
#pragma unroll
    for (int k = 0; k < NBINS / 256; k++) {
        local[k] = counts[tid * (NBINS / 256) + k];
        sum += local[k];
    }
    part[tid] = sum;
    __syncthreads();
    if (tid == 0) {
        int acc = 0;
        for (int i = 0; i < 256; i++) {
            int t = part[i];
            part[i] = acc;
            acc += t;
        }
        starts[NBINS] = acc;
    }
    __syncthreads();
    int acc = part[tid];
#pragma unroll
    for (int k = 0; k < NBINS / 256; k++) {
        starts[tid * (NBINS / 256) + k] = acc;
        acc += local[k];
    }
}

__global__ __launch_bounds__(256) void scatter_kernel(const float* __restrict__ pos,
                                                      const float* __restrict__ cell,
                                                      const int* __restrict__ starts,
                                                      int* __restrict__ cursor,
                                                      int* __restrict__ binatoms, int n) {
    int i = blockIdx.x * blockDim.x + threadIdx.x;
    if (i >= n) return;
    float inv[9], det;
    inv3x3(cell, inv, &det);
    int base[3];
    float fp[3];
    atom_base(pos, inv, i, base, fp);
    int bid = ((base[0] >> 3) << 8) | ((base[1] >> 3) << 4) | (base[2] >> 3);
    int slot = atomicAdd(&cursor[bid], 1);
    binatoms[starts[bid] + slot] = i;
}

// ---------------- binned LDS-privatized spreading -> private tiles ----------------
__global__ __launch_bounds__(256) void spread_bins_kernel(
    const float* __restrict__ pos, const float* __restrict__ chg,
    const float* __restrict__ cell, const int* __restrict__ starts,
    const int* __restrict__ binatoms, float* __restrict__ tiles) {
    __shared__ float tile[TILE_N];
    __shared__ float awx[64][4], awy[64][4], awz[64][4];
    __shared__ int aloc[64];
    int tid = threadIdx.x;
    int bid = blockIdx.x;
    int bx = bid >> 8, by = (bid >> 4) & 15, bz = bid & 15;
    for (int i = tid; i < TILE_N; i += 256) tile[i] = 0.0f;
    float inv[9], det;
    inv3x3(cell, inv, &det);
    int s = starts[bid], e = starts[bid + 1];
    for (int c0 = s; c0 < e; c0 += 64) {
        int cnt = min(64, e - c0);
        if (tid < cnt) {
            int a = binatoms[c0 + tid];
            int base[3];
            float fp[3];
            atom_base(pos, inv, a, base, fp);
            float w[4], dw[4];
            float qi = chg[a];
            bspline4(fp[0], w, dw);
#pragma unroll
            for (int j = 0; j < 4; j++) awx[tid][j] = qi * w[j];
            bspline4(fp[1], w, dw);
#pragma unroll
            for (int j = 0; j < 4; j++) awy[tid][j] = w[j];
            bspline4(fp[2], w, dw);
#pragma unroll
            for (int j = 0; j < 4; j++) awz[tid][j] = w[j];
            aloc[tid] = (base[0] - (bx << 3)) | ((base[1] - (by << 3)) << 4) |
                        ((base[2] - (bz << 3)) << 8);
        }
        __syncthreads();
        int items = cnt << 4;
        for (int it = tid; it < items; it += 256) {
            int a = it >> 4, r = it & 15, j0 = r >> 2, j1 = r & 3;
            int lc = aloc[a];
            int lx = (lc & 15) + j0;
            int ly = ((lc >> 4) & 15) + j1;
            int lz = lc >> 8;
            float val = awx[a][j0] * awy[a][j1];
            int tb = (lx * TILE_D + ly) * TILE_D + lz;
#pragma unroll
            for (int j2 = 0; j2 < 4; j2++) atomicAdd(&tile[tb + j2], val * awz[a][j2]);
        }
        __syncthreads();
    }
    float* tout = tiles + (size_t)bid * TSTRIDE;
    for (int i = tid; i < TILE_N; i += 256) tout[i] = tile[i];
}

// ---------------- merge private tiles -> mesh (plain loads/stores, no atomics) -------
__global__ __launch_bounds__(256) void merge_tiles_kernel(const float* __restrict__ tiles,
                                                          float2* __restrict__ C) {
    int idx = blockIdx.x * 256 + threadIdx.x;
    int gx = idx >> 14, gy = (idx >> 7) & 127, gz = idx & 127;
    int bx = gx >> 3, ox = gx & 7;
    int by = gy >> 3, oy = gy & 7;
    int bz = gz >> 3, oz = gz & 7;
    int nx = (ox >= 5) ? 2 : 1, ny = (oy >= 5) ? 2 : 1, nz = (oz >= 5) ? 2 : 1;
    int bxs[2] = {bx, (bx + 1) & 15}, lxs[2] = {ox + 3, ox - 5};
    int bys[2] = {by, (by + 1) & 15}, lys[2] = {oy + 3, oy - 5};
    int bzs[2] = {bz, (bz + 1) & 15}, lzs[2] = {oz + 3, oz - 5};
    float v = 0.0f;
    for (int i = 0; i < nx; i++)
        for (int j = 0; j < ny; j++) {
            int bxy = (bxs[i] << 8) | (bys[j] << 4);
            int lo = lxs[i] * (TILE_D * TILE_D) + lys[j] * TILE_D;
            for (int k = 0; k < nz; k++)
                v += tiles[(size_t)(bxy | bzs[k]) * TSTRIDE + lo + lzs[k]];
        }
    C[idx] = make_float2(v, 0.0f);
}

// ---------------- wave-level 128-point FFT: 2 complex per lane, shuffles only --------
__device__ __forceinline__ float2 cmul(float2 a, float cs, float sn) {
    return make_float2(a.x * cs - a.y * sn, a.x * sn + a.y * cs);
}

// Input: v0 = element at brev slot l, v1 = slot l+64. Output natural: v0=el l, v1=el l+64.
__device__ __forceinline__ void wave_fft128(float2& v0, float2& v1, int l, float sign) {
#pragma unroll
    for (int m = 1; m <= 32; m <<= 1) {
        float2 p0, p1;
        p0.x = __shfl_xor(v0.x, m);
        p0.y = __shfl_xor(v0.y, m);
        p1.x = __shfl_xor(v1.x, m);
        p1.y = __shfl_xor(v1.y, m);
        float ang = sign * (PI_F / (float)m) * (float)(l & (m - 1));
        float sn, cs;
        __sincosf(ang, &sn, &cs);
        bool hi = (l & m) != 0;
        float2 o0 = hi ? v0 : p0, e0 = hi ? p0 : v0;
        float2 o1 = hi ? v1 : p1, e1 = hi ? p1 : v1;
        float2 t0 = cmul(o0, cs, sn);
        float2 t1 = cmul(o1, cs, sn);
        float s = hi ? -1.0f : 1.0f;
        v0 = make_float2(e0.x + s * t0.x, e0.y + s * t0.y);
        v1 = make_float2(e1.x + s * t1.x, e1.y + s * t1.y);
    }
    float ang = sign * (PI_F / 64.0f) * (float)l;
    float sn, cs;
    __sincosf(ang, &sn, &cs);
    float2 t = cmul(v1, cs, sn);
    float2 e = v0;
    v0 = make_float2(e.x + t.x, e.y + t.y);
    v1 = make_float2(e.x - t.x, e.y - t.y);
}

// FFT along z (contiguous lines). 8 lines per block, one wave each. No LDS.
__global__ __launch_bounds__(512) void fft_z(float2* __restrict__ C, float sign) {
    int w = threadIdx.x >> 6, l = threadIdx.x & 63;
    int line = (blockIdx.x << 3) + w;
    int base = line << 7;
    int r = brev7(l);  // even; brev7(l+64) = r+1
    float4 f = ((const float4*)C)[(line << 6) + (r >> 1)];
    float2 v0 = make_float2(f.x, f.y);
    float2 v1 = make_float2(f.z, f.w);
    wave_fft128(v0, v1, l, sign);
    C[base + l] = v0;
    C[base + l + 64] = v1;
}

// FFT along a strided dim. Block: 8 lines sharing 8 consecutive z; LDS transpose stage.
__global__ __launch_bounds__(512) void fft_t(float2* __restrict__ C, int LS, int OS,
                                             float sign) {
    __shared__ float2 lds[128 * 9];
    int tid = threadIdx.x;
    int p = blockIdx.x >> 4;
    int z0 = (blockIdx.x & 15) << 3;
    int base = p * OS + z0;
    {
        int ll = tid >> 2, zq = tid & 3;
        float4 f = ((const float4*)C)[(base >> 1) + ll * (LS >> 1) + zq];
        lds[ll * 9 + 2 * zq] = make_float2(f.x, f.y);
        lds[ll * 9 + 2 * zq + 1] = make_float2(f.z, f.w);
    }
    __syncthreads();
    int w = tid >> 6, l = tid & 63;
    int r = brev7(l);
    float2 v0 = lds[r * 9 + w];
    float2 v1 = lds[(r + 1) * 9 + w];
    wave_fft128(v0, v1, l, sign);
    lds[l * 9 + w] = v0;
    lds[(l + 64) * 9 + w] = v1;
    __syncthreads();
    {
        int ll = tid >> 2, zq = tid & 3;
        float2 a = lds[ll * 9 + 2 * zq];
        float2 b = lds[ll * 9 + 2 * zq + 1];
        ((float4*)C)[(base >> 1) + ll * (LS >> 1) + zq] = make_float4(a.x, a.y, b.x, b.y);
    }
}

// ---------------- |b(m)|^-2 table ----------------
__device__ __forceinline__ float bmod2f(int x) {
    float th = (TWO_PI_F / (float)KDIM) * (float)x;
    float s1, c1, s2, c2;
    __sincosf(th, &s1, &c1);
    __sincosf(th + th, &s2, &c2);
    float dr = 0.16666667f + 0.66666667f * c1 + 0.16666667f * c2;
    float di = 0.66666667f * s1 + 0.16666667f * s2;
    float d2 = dr * dr + di * di;
    return 1.0f / fmaxf(d2, 1e-12f);
}

__global__ void btbl_kernel(float* __restrict__ btbl) {
    int i = threadIdx.x;
    if (i < KDIM) btbl[i] = bmod2f(i);
}

// --------- fused: forward x-FFT + reciprocal scale + energy + inverse x-FFT ---------
__global__ __launch_bounds__(512) void fft_x_scale(float2* __restrict__ C,
                                                   const float* __restrict__ cell,
                                                   const float* __restrict__ btbl,
                                                   float* __restrict__ scale_part) {
    __shared__ float2 lds[128 * 9];
    __shared__ float red[8];
    const int LS = KDIM * KDIM, OS = KDIM;
    int tid = threadIdx.x;
    int p = blockIdx.x >> 4;            // y index
    int z0 = (blockIdx.x & 15) << 3;
    int base = p * OS + z0;
    {
        int ll = tid >> 2, zq = tid & 3;
        float4 f = ((const float4*)C)[(base >> 1) + ll * (LS >> 1) + zq];
        lds[ll * 9 + 2 * zq] = make_float2(f.x, f.y);
        lds[ll * 9 + 2 * zq + 1] = make_float2(f.z, f.w);
    }
    __syncthreads();
    int w = tid >> 6, l = tid & 63;
    int r = brev7(l);
    float2 v0 = lds[r * 9 + w];
    float2 v1 = lds[(r + 1) * 9 + w];
    wave_fft128(v0, v1, l, -1.0f);
    // scale: v0 is x-element l, v1 is x-element l+64; y = p, z = z0 + w
    float inv[9], det;
    inv3x3(cell, inv, &det);
    int y = p, z = z0 + w;
    float my = (float)(y < 64 ? y : y - 128);
    float mz = (float)(z < 64 ? z : z - 128);
    float byz = btbl[y] * btbl[z];
    float contrib = 0.0f;
#pragma unroll
    for (int h = 0; h < 2; h++) {
        int x = l + (h << 6);
        float mx = (float)(x < 64 ? x : x - 128);
        float kx = TWO_PI_F * (mx * inv[0] + my * inv[1] + mz * inv[2]);
        float ky = TWO_PI_F * (mx * inv[3] + my * inv[4] + mz * inv[5]);
        float kz = TWO_PI_F * (mx * inv[6] + my * inv[7] + mz * inv[8]);
        float k2 = kx * kx + ky * ky + kz * kz;
        float A = 0.0f;
        if (k2 > 0.0f)
            A = __expf(-k2 / (4.0f * ALPHA_F * ALPHA_F)) / k2 * btbl[x] * byz;
        float2& v = h ? v1 : v0;
        contrib += A * (v.x * v.x + v.y * v.y);
        v.x *= A;
        v.y *= A;
    }
    // re-stage for bit-reversed read (same-wave column -> wave-synchronous, no barrier)
    lds[l * 9 + w] = v0;
    lds[(l + 64) * 9 + w] = v1;
    float2 u0 = lds[r * 9 + w];
    float2 u1 = lds[(r + 1) * 9 + w];
    wave_fft128(u0, u1, l, 1.0f);
    lds[l * 9 + w] = u0;
    lds[(l + 64) * 9 + w] = u1;
    // energy partial
#pragma unroll
    for (int off = 32; off; off >>= 1) contrib += __shfl_down(contrib, off);
    if (l == 0) red[w] = contrib;
    __syncthreads();
    if (tid == 0) {
        float v = 0.0f;
        for (int i = 0; i < 8; i++) v += red[i];
        scale_part[blockIdx.x] = v;
    }
    {
        int ll = tid >> 2, zq = tid & 3;
        float2 a = lds[ll * 9 + 2 * zq];
        float2 b = lds[ll * 9 + 2 * zq + 1];
        ((float4*)C)[(base >> 1) + ll * (LS >> 1) + zq] = make_float4(a.x, a.y, b.x, b.y);
    }
}

// ---------------- energy finalize ----------------
__global__ __launch_bounds__(256) void finalize_kernel(const float* __restrict__ scale_part,
                                                       const float* __restrict__ q2_part,
                                                       int nq2,
                                                       const float* __restrict__ cell,
                                                       float* __restrict__ out) {
    __shared__ double sd[256];
    int tid = threadIdx.x;
    double es = 0.0;
    for (int i = tid; i < NSCALE_BLK; i += 256) es += (double)scale_part[i];
    double q2 = 0.0;
    for (int i = tid; i < nq2; i += 256) q2 += (double)q2_part[i];
    sd[tid] = es;
    __syncthreads();
    for (int s = 128; s; s >>= 1) {
        if (tid < s) sd[tid] += sd[tid + s];
        __syncthreads();
    }
    double esum = sd[0];
    __syncthreads();
    sd[tid] = q2;
    __syncthreads();
    for (int s = 128; s; s >>= 1) {
        if (tid < s) sd[tid] += sd[tid + s];
        __syncthreads();
    }
    if (tid == 0) {
        float inv[9], det;
        inv3x3(cell, inv, &det);
        double c = (double)KE_F * 2.0 * 3.14159265358979323846 / (double)det;
        double e = c * esum -
                   (double)KE_F * (double)ALPHA_F / 1.7724538509055160273 * sd[0];
        out[0] = (float)e;
    }
}

// ---------------- force gather ----------------
__global__ __launch_bounds__(256) void gather_kernel(const float* __restrict__ pos,
                                                     const float* __restrict__ chg,
                                                     const float* __restrict__ cell,
                                                     const float2* __restrict__ C,
                                                     float* __restrict__ out, int n) {
    int i = blockIdx.x * blockDim.x + threadIdx.x;
    if (i >= n) return;
    float inv[9], det;
    inv3x3(cell, inv, &det);
    float wgt[3][4], dwg[3][4];
    int idx[3][4];
    atom_setup(pos, inv, i, wgt, dwg, idx);
    float acc0 = 0.0f, acc1 = 0.0f, acc2 = 0.0f;
#pragma unroll
    for (int j0 = 0; j0 < 4; j0++) {
        int r0 = idx[0][j0] << 14;
        float wx = wgt[0][j0], dx = dwg[0][j0];
#pragma unroll
        for (int j1 = 0; j1 < 4; j1++) {
            int r1 = r0 + (idx[1][j1] << 7);
            float wy = wgt[1][j1], dy = dwg[1][j1];
            float c00 = wx * wy;
            float c01 = wx * dy;
            float c02 = dx * wy;
#pragma unroll
            for (int j2 = 0; j2 < 4; j2++) {
                float phi = C[r1 + idx[2][j2]].x;
                float wz = wgt[2][j2], dz = dwg[2][j2];
                acc0 += phi * c02 * wz;
                acc1 += phi * c01 * wz;
                acc2 += phi * c00 * dz;
            }
        }
    }
    float qi = chg[i];
    float c = KE_F * TWO_PI_F / det;
    float fac = -2.0f * c * qi * (float)KDIM;
    float F0 = fac * (acc0 * inv[0] + acc1 * inv[1] + acc2 * inv[2]);
    float F1 = fac * (acc0 * inv[3] + acc1 * inv[4] + acc2 * inv[5]);
    float F2 = fac * (acc0 * inv[6] + acc1 * inv[7] + acc2 * inv[8]);
    out[1 + 3 * i + 0] = F0;
    out[1 + 3 * i + 1] = F1;
    out[1 + 3 * i + 2] = F2;
}

extern "C" void kernel_launch(void* const* d_in, const int* in_sizes, int n_in,
                              void* d_out, int out_size, void* d_ws, size_t ws_size,
                              hipStream_t stream) {
    const float* pos = (const float*)d_in[0];
    const float* chg = (const float*)d_in[1];
    const float* cell = (const float*)d_in[2];
    float* out = (float*)d_out;
    int n = in_sizes[1];
    int nb = (n + 255) / 256;

    char* w = (char*)d_ws;
    float2* C = (float2*)w;                       // 16.8 MB
    size_t off = (size_t)NTOT * sizeof(float2);
    float* tiles = (float*)(w + off);             // 22.0 MB
    off += (size_t)NBINS * TSTRIDE * sizeof(float);
    int* counts = (int*)(w + off);                // NBINS (zeroed)
    size_t zoff = off;
    off += NBINS * sizeof(int);
    int* cursor = (int*)(w + off);                // NBINS (zeroed)
    off += NBINS * sizeof(int);
    size_t zero_bytes = off - zoff;
    int* starts = (int*)(w + off);                // NBINS+1
    off += (NBINS + 1) * sizeof(int);
    int* binatoms = (int*)(w + off);              // n
    off += (size_t)n * sizeof(int);
    float* scale_part = (float*)(w + off);        // NSCALE_BLK
    off += NSCALE_BLK * sizeof(float);
    float* q2_part = (float*)(w + off);           // nb
    off += (size_t)nb * sizeof(float);
    float* btbl = (float*)(w + off);              // 128

    hipMemsetAsync(w + zoff, 0, zero_bytes, stream);

    btbl_kernel<<<1, 128, 0, stream>>>(btbl);
    hist_kernel<<<nb, 256, 0, stream>>>(pos, chg, cell, counts, q2_part, n);
    scan_kernel<<<1, 256, 0, stream>>>(counts, starts);
    scatter_kernel<<<nb, 256, 0, stream>>>(pos, cell, starts, cursor, binatoms, n);
    spread_bins_kernel<<<NBINS, 256, 0, stream>>>(pos, chg, cell, starts, binatoms, tiles);
    merge_tiles_kernel<<<NTOT / 256, 256, 0, stream>>>(tiles, C);

    // forward z, y
    fft_z<<<2048, 512, 0, stream>>>(C, -1.0f);
    fft_t<<<2048, 512, 0, stream>>>(C, KDIM, KDIM * KDIM, -1.0f);      // y dim
    // fused forward x + scale + inverse x
    fft_x_scale<<<NSCALE_BLK, 512, 0, stream>>>(C, cell, btbl, scale_part);
    // inverse y, z
    fft_t<<<2048, 512, 0, stream>>>(C, KDIM, KDIM * KDIM, 1.0f);
    fft_z<<<2048, 512, 0, stream>>>(C, 1.0f);

    finalize_kernel<<<1, 256, 0, stream>>>(scale_part, q2_part, nb, cell, out);
    gather_kernel<<<nb, 256, 0, stream>>>(pos, chg, cell, C, out, n);
}

// Round 5
// 235.561 us; speedup vs baseline: 3.8859x; 1.1705x over previous
//
#include <hip/hip_runtime.h>

#define KDIM 128
#define NTOT (KDIM * KDIM * KDIM)
#define BPD 16          // bins per dim
#define NBINS (BPD * BPD * BPD)
#define TILE_D 11       // 8 + 3 overlap
#define TILE_N (TILE_D * TILE_D * TILE_D)
#define TSTRIDE 1344    // padded tile stride (floats)
#define NSCALE_BLK 1024
#define ST 17           // LDS row stride (float2) for transpose stages

static constexpr float PI_F = 3.14159265358979323846f;
static constexpr float TWO_PI_F = 6.28318530717958647692f;
static constexpr float KE_F = 14.3996f;
static constexpr float ALPHA_F = 0.35f;

__device__ __forceinline__ int brev7(int i) { return (int)(__brev((unsigned)i) >> 25); }

__device__ __forceinline__ void inv3x3(const float* c, float* inv, float* adet) {
    float a00 = c[0], a01 = c[1], a02 = c[2];
    float a10 = c[3], a11 = c[4], a12 = c[5];
    float a20 = c[6], a21 = c[7], a22 = c[8];
    float det = a00 * (a11 * a22 - a12 * a21) - a01 * (a10 * a22 - a12 * a20) +
                a02 * (a10 * a21 - a11 * a20);
    float id = 1.0f / det;
    inv[0] = (a11 * a22 - a12 * a21) * id;
    inv[1] = (a02 * a21 - a01 * a22) * id;
    inv[2] = (a01 * a12 - a02 * a11) * id;
    inv[3] = (a12 * a20 - a10 * a22) * id;
    inv[4] = (a00 * a22 - a02 * a20) * id;
    inv[5] = (a02 * a10 - a00 * a12) * id;
    inv[6] = (a10 * a21 - a11 * a20) * id;
    inv[7] = (a01 * a20 - a00 * a21) * id;
    inv[8] = (a00 * a11 - a01 * a10) * id;
    *adet = fabsf(det);
}

__device__ __forceinline__ void bspline4(float f, float* w, float* dw) {
    float f2 = f * f, f3 = f2 * f;
    float omf = 1.0f - f;
    w[0] = omf * omf * omf * (1.0f / 6.0f);
    w[1] = (3.0f * f3 - 6.0f * f2 + 4.0f) * (1.0f / 6.0f);
    w[2] = (-3.0f * f3 + 3.0f * f2 + 3.0f * f + 1.0f) * (1.0f / 6.0f);
    w[3] = f3 * (1.0f / 6.0f);
    dw[0] = -0.5f * omf * omf;
    dw[1] = 1.5f * f2 - 2.0f * f;
    dw[2] = -1.5f * f2 + f + 0.5f;
    dw[3] = 0.5f * f2;
}

__device__ __forceinline__ void atom_base(const float* __restrict__ pos, const float* inv,
                                          int i, int base[3], float fpart[3]) {
    float p0 = pos[3 * i], p1 = pos[3 * i + 1], p2 = pos[3 * i + 2];
#pragma unroll
    for (int d = 0; d < 3; d++) {
        float fr = p0 * inv[d] + p1 * inv[3 + d] + p2 * inv[6 + d];
        fr -= floorf(fr);
        float u = fr * (float)KDIM;
        float bs = floorf(u);
        fpart[d] = u - bs;
        int b = (int)bs;
        base[d] = b & (KDIM - 1);
    }
}

__device__ __forceinline__ void atom_setup(const float* __restrict__ pos, const float* inv,
                                           int i, float wgt[3][4], float dwg[3][4],
                                           int idx[3][4]) {
    int base[3];
    float fp[3];
    atom_base(pos, inv, i, base, fp);
#pragma unroll
    for (int d = 0; d < 3; d++) {
        bspline4(fp[d], wgt[d], dwg[d]);
#pragma unroll
        for (int j = 0; j < 4; j++) idx[d][j] = (base[d] - 3 + j + KDIM) & (KDIM - 1);
    }
}

// ---------------- binning: histogram + per-block sum(q^2) ----------------
__global__ __launch_bounds__(256) void hist_kernel(const float* __restrict__ pos,
                                                   const float* __restrict__ chg,
                                                   const float* __restrict__ cell,
                                                   int* __restrict__ counts,
                                                   float* __restrict__ q2_part, int n) {
    __shared__ float hred[4];
    int i = blockIdx.x * blockDim.x + threadIdx.x;
    float q2 = 0.0f;
    if (i < n) {
        float inv[9], det;
        inv3x3(cell, inv, &det);
        int base[3];
        float fp[3];
        atom_base(pos, inv, i, base, fp);
        int bid = ((base[0] >> 3) << 8) | ((base[1] >> 3) << 4) | (base[2] >> 3);
        atomicAdd(&counts[bid], 1);
        float qi = chg[i];
        q2 = qi * qi;
    }
#pragma unroll
    for (int off = 32; off; off >>= 1) q2 += __shfl_down(q2, off);
    if ((threadIdx.x & 63) == 0) hred[threadIdx.x >> 6] = q2;
    __syncthreads();
    if (threadIdx.x == 0) q2_part[blockIdx.x] = hred[0] + hred[1] + hred[2] + hred[3];
}

__global__ __launch_bounds__(256) void scan_kernel(const int* __restrict__ counts,
                                                   int* __restrict__ starts) {
    __shared__ int part[256];
    int tid = threadIdx.x;
    int local[NBINS / 256];
    int sum = 0;
#pragma unroll
    for (int k = 0; k < NBINS / 256; k++) {
        local[k] = counts[tid * (NBINS / 256) + k];
        sum += local[k];
    }
    part[tid] = sum;
    __syncthreads();
    if (tid == 0) {
        int acc = 0;
        for (int i = 0; i < 256; i++) {
            int t = part[i];
            part[i] = acc;
            acc += t;
        }
        starts[NBINS] = acc;
    }
    __syncthreads();
    int acc = part[tid];
#pragma unroll
    for (int k = 0; k < NBINS / 256; k++) {
        starts[tid * (NBINS / 256) + k] = acc;
        acc += local[k];
    }
}

// scatter: compute weights once, write 64B record per atom in bin-sorted order
// record: [0..3]=q*wx, [4..7]=wy, [8..11]=wz, [12]=loc bits, [13..15]=pad
__global__ __launch_bounds__(256) void scatter_kernel(const float* __restrict__ pos,
                                                      const float* __restrict__ chg,
                                                      const float* __restrict__ cell,
                                                      const int* __restrict__ starts,
                                                      int* __restrict__ cursor,
                                                      float* __restrict__ records, int n) {
    int i = blockIdx.x * blockDim.x + threadIdx.x;
    if (i >= n) return;
    float inv[9], det;
    inv3x3(cell, inv, &det);
    int base[3];
    float fp[3];
    atom_base(pos, inv, i, base, fp);
    int bx = base[0] >> 3, by = base[1] >> 3, bz = base[2] >> 3;
    int bid = (bx << 8) | (by << 4) | bz;
    int slot = atomicAdd(&cursor[bid], 1);
    float4* rec = (float4*)(records + (size_t)(starts[bid] + slot) * 16);
    float w[4], dw[4];
    float qi = chg[i];
    bspline4(fp[0], w, dw);
    rec[0] = make_float4(qi * w[0], qi * w[1], qi * w[2], qi * w[3]);
    bspline4(fp[1], w, dw);
    rec[1] = make_float4(w[0], w[1], w[2], w[3]);
    bspline4(fp[2], w, dw);
    rec[2] = make_float4(w[0], w[1], w[2], w[3]);
    int loc = (base[0] - (bx << 3)) | ((base[1] - (by << 3)) << 4) |
              ((base[2] - (bz << 3)) << 8);
    rec[3] = make_float4(__int_as_float(loc), 0.0f, 0.0f, 0.0f);
}

// ---------------- binned LDS-privatized spreading -> private tiles ----------------
__global__ __launch_bounds__(256) void spread_bins_kernel(
    const float* __restrict__ records, const int* __restrict__ starts,
    float* __restrict__ tiles) {
    __shared__ float tile[TILE_N];
    __shared__ float4 arec[256 * 4];
    int tid = threadIdx.x;
    int bid = blockIdx.x;
    for (int i = tid; i < TILE_N; i += 256) tile[i] = 0.0f;
    int s = starts[bid], e = starts[bid + 1];
    for (int c0 = s; c0 < e; c0 += 256) {
        int cnt = min(256, e - c0);
        __syncthreads();
        if (tid < cnt) {
            const float4* rp = (const float4*)records + (size_t)(c0 + tid) * 4;
            arec[tid * 4 + 0] = rp[0];
            arec[tid * 4 + 1] = rp[1];
            arec[tid * 4 + 2] = rp[2];
            arec[tid * 4 + 3] = rp[3];
        }
        __syncthreads();
        int items = cnt << 4;
        for (int it = tid; it < items; it += 256) {
            int a = it >> 4, r = it & 15, j0 = r >> 2, j1 = r & 3;
            const float* A = (const float*)&arec[a << 2];
            float val = A[j0] * A[4 + j1];
            int lc = __float_as_int(A[12]);
            int lx = (lc & 15) + j0;
            int ly = ((lc >> 4) & 15) + j1;
            int lz = lc >> 8;
            int tb = (lx * TILE_D + ly) * TILE_D + lz;
#pragma unroll
            for (int j2 = 0; j2 < 4; j2++) atomicAdd(&tile[tb + j2], val * A[8 + j2]);
        }
    }
    __syncthreads();
    float* tout = tiles + (size_t)bid * TSTRIDE;
    for (int i = tid; i < TILE_N; i += 256) tout[i] = tile[i];
}

// ---------------- wave FFTs: DIF (natural->scrambled), DIT (scrambled->natural) ------
__device__ __forceinline__ float2 cmul(float2 a, float cs, float sn) {
    return make_float2(a.x * cs - a.y * sn, a.x * sn + a.y * cs);
}

__device__ __forceinline__ void wave_fft128_dif(float2& v0, float2& v1, int l, float sign) {
    {
        float ang = sign * (PI_F / 64.0f) * (float)l;
        float sn, cs;
        __sincosf(ang, &sn, &cs);
        float2 d = make_float2(v0.x - v1.x, v0.y - v1.y);
        v0 = make_float2(v0.x + v1.x, v0.y + v1.y);
        v1 = cmul(d, cs, sn);
    }
#pragma unroll
    for (int m = 32; m >= 1; m >>= 1) {
        float ang = sign * (PI_F / (float)m) * (float)(l & (m - 1));
        float sn, cs;
        __sincosf(ang, &sn, &cs);
        bool hi = (l & m) != 0;
        float2 p0, p1;
        p0.x = __shfl_xor(v0.x, m);
        p0.y = __shfl_xor(v0.y, m);
        p1.x = __shfl_xor(v1.x, m);
        p1.y = __shfl_xor(v1.y, m);
        float2 a0 = hi ? cmul(make_float2(p0.x - v0.x, p0.y - v0.y), cs, sn)
                       : make_float2(v0.x + p0.x, v0.y + p0.y);
        float2 a1 = hi ? cmul(make_float2(p1.x - v1.x, p1.y - v1.y), cs, sn)
                       : make_float2(v1.x + p1.x, v1.y + p1.y);
        v0 = a0;
        v1 = a1;
    }
}

__device__ __forceinline__ void wave_fft128_dit(float2& v0, float2& v1, int l, float sign) {
#pragma unroll
    for (int m = 1; m <= 32; m <<= 1) {
        float2 p0, p1;
        p0.x = __shfl_xor(v0.x, m);
        p0.y = __shfl_xor(v0.y, m);
        p1.x = __shfl_xor(v1.x, m);
        p1.y = __shfl_xor(v1.y, m);
        float ang = sign * (PI_F / (float)m) * (float)(l & (m - 1));
        float sn, cs;
        __sincosf(ang, &sn, &cs);
        bool hi = (l & m) != 0;
        float2 o0 = hi ? v0 : p0, e0 = hi ? p0 : v0;
        float2 o1 = hi ? v1 : p1, e1 = hi ? p1 : v1;
        float2 t0 = cmul(o0, cs, sn);
        float2 t1 = cmul(o1, cs, sn);
        float s = hi ? -1.0f : 1.0f;
        v0 = make_float2(e0.x + s * t0.x, e0.y + s * t0.y);
        v1 = make_float2(e1.x + s * t1.x, e1.y + s * t1.y);
    }
    float ang = sign * (PI_F / 64.0f) * (float)l;
    float sn, cs;
    __sincosf(ang, &sn, &cs);
    float2 t = cmul(v1, cs, sn);
    float2 e = v0;
    v0 = make_float2(e.x + t.x, e.y + t.y);
    v1 = make_float2(e.x - t.x, e.y - t.y);
}

// ---- forward z FFT with merge of private tiles fused in (no C read, no merge pass) --
__global__ __launch_bounds__(512) void fft_z_merge(const float* __restrict__ tiles,
                                                   float2* __restrict__ C) {
    int w = threadIdx.x >> 6, l = threadIdx.x & 63;
    int line = (blockIdx.x << 3) + w;
    int gx = line >> 7, gy = line & 127;
    int bx = gx >> 3, ox = gx & 7;
    int by = gy >> 3, oy = gy & 7;
    int nx = (ox >= 5) ? 2 : 1, ny = (oy >= 5) ? 2 : 1;
    int bxs[2] = {bx, (bx + 1) & 15}, lxs[2] = {ox + 3, ox - 5};
    int bys[2] = {by, (by + 1) & 15}, lys[2] = {oy + 3, oy - 5};
    float2 v0, v1;
#pragma unroll
    for (int h = 0; h < 2; h++) {
        int gz = l + (h << 6);
        int bz = gz >> 3, oz = gz & 7;
        int nz = (oz >= 5) ? 2 : 1;
        int bzs[2] = {bz, (bz + 1) & 15}, lzs[2] = {oz + 3, oz - 5};
        float v = 0.0f;
        for (int i = 0; i < nx; i++)
            for (int j = 0; j < ny; j++) {
                int bxy = (bxs[i] << 8) | (bys[j] << 4);
                int lo = lxs[i] * (TILE_D * TILE_D) + lys[j] * TILE_D;
                for (int k = 0; k < nz; k++)
                    v += tiles[(size_t)(bxy | bzs[k]) * TSTRIDE + lo + lzs[k]];
            }
        if (h == 0) v0 = make_float2(v, 0.0f);
        else v1 = make_float2(v, 0.0f);
    }
    wave_fft128_dif(v0, v1, l, -1.0f);
    int base = line << 7;
    C[base + l] = v0;
    C[base + l + 64] = v1;
}

// ---- inverse z FFT (DIT), writes real potential mesh as float ----
__global__ __launch_bounds__(512) void fft_z_phi(const float2* __restrict__ C,
                                                 float* __restrict__ phi) {
    int w = threadIdx.x >> 6, l = threadIdx.x & 63;
    int line = (blockIdx.x << 3) + w;
    int base = line << 7;
    float2 v0 = C[base + l];
    float2 v1 = C[base + l + 64];
    wave_fft128_dit(v0, v1, l, 1.0f);
    phi[base + l] = v0.x;
    phi[base + l + 64] = v1.x;
}

// ---- FFT along strided dim (y). DIF=1 fwd, DIF=0 inv. 16-z chunks, LDS transpose. ---
template <int DIF>
__global__ __launch_bounds__(512) void fft_t(float2* __restrict__ C, int LS, int OS,
                                             float sign) {
    __shared__ float2 lds[128 * ST];
    int tid = threadIdx.x;
    int p = blockIdx.x >> 3;
    int z0 = (blockIdx.x & 7) << 4;
    int base = p * OS + z0;
#pragma unroll
    for (int k = 0; k < 2; k++) {
        int e = tid + (k << 9);
        int ll = e >> 3, zq = e & 7;
        float4 f = ((const float4*)C)[(base >> 1) + ll * (LS >> 1) + zq];
        lds[ll * ST + 2 * zq] = make_float2(f.x, f.y);
        lds[ll * ST + 2 * zq + 1] = make_float2(f.z, f.w);
    }
    __syncthreads();
    int w = tid >> 6, l = tid & 63;
#pragma unroll
    for (int c = 0; c < 2; c++) {
        int zt = (w << 1) | c;
        float2 v0 = lds[l * ST + zt];
        float2 v1 = lds[(l + 64) * ST + zt];
        if (DIF) wave_fft128_dif(v0, v1, l, sign);
        else wave_fft128_dit(v0, v1, l, sign);
        lds[l * ST + zt] = v0;
        lds[(l + 64) * ST + zt] = v1;
    }
    __syncthreads();
#pragma unroll
    for (int k = 0; k < 2; k++) {
        int e = tid + (k << 9);
        int ll = e >> 3, zq = e & 7;
        float2 a = lds[ll * ST + 2 * zq];
        float2 b = lds[ll * ST + 2 * zq + 1];
        ((float4*)C)[(base >> 1) + ll * (LS >> 1) + zq] = make_float4(a.x, a.y, b.x, b.y);
    }
}

// ---------------- scrambled-order m and |b|^-2 tables ----------------
__device__ __forceinline__ float bmod2f(int x) {
    float th = (TWO_PI_F / (float)KDIM) * (float)x;
    float s1, c1, s2, c2;
    __sincosf(th, &s1, &c1);
    __sincosf(th + th, &s2, &c2);
    float dr = 0.16666667f + 0.66666667f * c1 + 0.16666667f * c2;
    float di = 0.66666667f * s1 + 0.16666667f * s2;
    float d2 = dr * dr + di * di;
    return 1.0f / fmaxf(d2, 1e-12f);
}

__global__ void tbl_kernel(float* __restrict__ mtblS, float* __restrict__ btblS) {
    int i = threadIdx.x;
    if (i < KDIM) {
        int r = brev7(i);
        mtblS[i] = (float)(r < 64 ? r : r - 128);
        btblS[i] = bmod2f(r);
    }
}

// --------- fused: fwd x-DIF + scale (scrambled order) + energy + inv x-DIT ---------
__global__ __launch_bounds__(512) void fft_x_scale(float2* __restrict__ C,
                                                   const float* __restrict__ cell,
                                                   const float* __restrict__ mtblS,
                                                   const float* __restrict__ btblS,
                                                   float* __restrict__ scale_part) {
    __shared__ float2 lds[128 * ST];
    __shared__ float red[8];
    const int LS = KDIM * KDIM, OS = KDIM;
    int tid = threadIdx.x;
    int p = blockIdx.x >> 3;            // y slot
    int z0 = (blockIdx.x & 7) << 4;     // z chunk
    int base = p * OS + z0;
#pragma unroll
    for (int k = 0; k < 2; k++) {
        int e = tid + (k << 9);
        int ll = e >> 3, zq = e & 7;
        float4 f = ((const float4*)C)[(base >> 1) + ll * (LS >> 1) + zq];
        lds[ll * ST + 2 * zq] = make_float2(f.x, f.y);
        lds[ll * ST + 2 * zq + 1] = make_float2(f.z, f.w);
    }
    __syncthreads();
    int w = tid >> 6, l = tid & 63;
    float inv[9], det;
    inv3x3(cell, inv, &det);
    float my = mtblS[p];
    float by = btblS[p];
    float contrib = 0.0f;
#pragma unroll
    for (int c = 0; c < 2; c++) {
        int zt = (w << 1) | c;
        float2 v0 = lds[l * ST + zt];
        float2 v1 = lds[(l + 64) * ST + zt];
        wave_fft128_dif(v0, v1, l, -1.0f);
        int z = z0 + zt;
        float mz = mtblS[z];
        float byz = by * btblS[z];
#pragma unroll
        for (int h = 0; h < 2; h++) {
            int xs = l + (h << 6);      // x slot
            float mx = mtblS[xs];
            float kx = TWO_PI_F * (mx * inv[0] + my * inv[1] + mz * inv[2]);
            float ky = TWO_PI_F * (mx * inv[3] + my * inv[4] + mz * inv[5]);
            float kz = TWO_PI_F * (mx * inv[6] + my * inv[7] + mz * inv[8]);
            float k2 = kx * kx + ky * ky + kz * kz;
            float A = 0.0f;
            if (k2 > 0.0f)
                A = __expf(-k2 / (4.0f * ALPHA_F * ALPHA_F)) / k2 * btblS[xs] * byz;
            float2& v = h ? v1 : v0;
            contrib += A * (v.x * v.x + v.y * v.y);
            v.x *= A;
            v.y *= A;
        }
        wave_fft128_dit(v0, v1, l, 1.0f);
        lds[l * ST + zt] = v0;
        lds[(l + 64) * ST + zt] = v1;
    }
#pragma unroll
    for (int off = 32; off; off >>= 1) contrib += __shfl_down(contrib, off);
    if (l == 0) red[w] = contrib;
    __syncthreads();
    if (tid == 0) {
        float v = 0.0f;
        for (int i = 0; i < 8; i++) v += red[i];
        scale_part[blockIdx.x] = v;
    }
#pragma unroll
    for (int k = 0; k < 2; k++) {
        int e = tid + (k << 9);
        int ll = e >> 3, zq = e & 7;
        float2 a = lds[ll * ST + 2 * zq];
        float2 b = lds[ll * ST + 2 * zq + 1];
        ((float4*)C)[(base >> 1) + ll * (LS >> 1) + zq] = make_float4(a.x, a.y, b.x, b.y);
    }
}

// ---------------- energy finalize ----------------
__global__ __launch_bounds__(256) void finalize_kernel(const float* __restrict__ scale_part,
                                                       const float* __restrict__ q2_part,
                                                       int nq2,
                                                       const float* __restrict__ cell,
                                                       float* __restrict__ out) {
    __shared__ double sd[256];
    int tid = threadIdx.x;
    double es = 0.0;
    for (int i = tid; i < NSCALE_BLK; i += 256) es += (double)scale_part[i];
    double q2 = 0.0;
    for (int i = tid; i < nq2; i += 256) q2 += (double)q2_part[i];
    sd[tid] = es;
    __syncthreads();
    for (int s = 128; s; s >>= 1) {
        if (tid < s) sd[tid] += sd[tid + s];
        __syncthreads();
    }
    double esum = sd[0];
    __syncthreads();
    sd[tid] = q2;
    __syncthreads();
    for (int s = 128; s; s >>= 1) {
        if (tid < s) sd[tid] += sd[tid + s];
        __syncthreads();
    }
    if (tid == 0) {
        float inv[9], det;
        inv3x3(cell, inv, &det);
        double c = (double)KE_F * 2.0 * 3.14159265358979323846 / (double)det;
        double e = c * esum -
                   (double)KE_F * (double)ALPHA_F / 1.7724538509055160273 * sd[0];
        out[0] = (float)e;
    }
}

// ---------------- force gather (reads float phi mesh) ----------------
__global__ __launch_bounds__(256) void gather_kernel(const float* __restrict__ pos,
                                                     const float* __restrict__ chg,
                                                     const float* __restrict__ cell,
                                                     const float* __restrict__ phi,
                                                     float* __restrict__ out, int n) {
    int i = blockIdx.x * blockDim.x + threadIdx.x;
    if (i >= n) return;
    float inv[9], det;
    inv3x3(cell, inv, &det);
    float wgt[3][4], dwg[3][4];
    int idx[3][4];
    atom_setup(pos, inv, i, wgt, dwg, idx);
    float acc0 = 0.0f, acc1 = 0.0f, acc2 = 0.0f;
#pragma unroll
    for (int j0 = 0; j0 < 4; j0++) {
        int r0 = idx[0][j0] << 14;
        float wx = wgt[0][j0], dx = dwg[0][j0];
#pragma unroll
        for (int j1 = 0; j1 < 4; j1++) {
            int r1 = r0 + (idx[1][j1] << 7);
            float wy = wgt[1][j1], dy = dwg[1][j1];
            float c00 = wx * wy;
            float c01 = wx * dy;
            float c02 = dx * wy;
#pragma unroll
            for (int j2 = 0; j2 < 4; j2++) {
                float p = phi[r1 + idx[2][j2]];
                float wz = wgt[2][j2], dz = dwg[2][j2];
                acc0 += p * c02 * wz;
                acc1 += p * c01 * wz;
                acc2 += p * c00 * dz;
            }
        }
    }
    float qi = chg[i];
    float c = KE_F * TWO_PI_F / det;
    float fac = -2.0f * c * qi * (float)KDIM;
    float F0 = fac * (acc0 * inv[0] + acc1 * inv[1] + acc2 * inv[2]);
    float F1 = fac * (acc0 * inv[3] + acc1 * inv[4] + acc2 * inv[5]);
    float F2 = fac * (acc0 * inv[6] + acc1 * inv[7] + acc2 * inv[8]);
    out[1 + 3 * i + 0] = F0;
    out[1 + 3 * i + 1] = F1;
    out[1 + 3 * i + 2] = F2;
}

extern "C" void kernel_launch(void* const* d_in, const int* in_sizes, int n_in,
                              void* d_out, int out_size, void* d_ws, size_t ws_size,
                              hipStream_t stream) {
    const float* pos = (const float*)d_in[0];
    const float* chg = (const float*)d_in[1];
    const float* cell = (const float*)d_in[2];
    float* out = (float*)d_out;
    int n = in_sizes[1];
    int nb = (n + 255) / 256;

    char* w = (char*)d_ws;
    float2* C = (float2*)w;                       // 16.78 MB; records alias this
    size_t off = (size_t)NTOT * sizeof(float2);
    float* tiles = (float*)(w + off);             // 22.02 MB; phi aliases this
    off += (size_t)NBINS * TSTRIDE * sizeof(float);
    int* counts = (int*)(w + off);                // NBINS (zeroed)
    size_t zoff = off;
    off += NBINS * sizeof(int);
    int* cursor = (int*)(w + off);                // NBINS (zeroed)
    off += NBINS * sizeof(int);
    size_t zero_bytes = off - zoff;
    int* starts = (int*)(w + off);                // NBINS+1
    off += (NBINS + 1) * sizeof(int);
    float* scale_part = (float*)(w + off);        // NSCALE_BLK
    off += NSCALE_BLK * sizeof(float);
    float* q2_part = (float*)(w + off);           // nb
    off += (size_t)nb * sizeof(float);
    float* mtblS = (float*)(w + off);             // 128
    off += KDIM * sizeof(float);
    float* btblS = (float*)(w + off);             // 128

    float* records = (float*)C;                   // dead until fft_z_merge rewrites C
    float* phi = (float*)tiles;                   // tiles dead after fft_z_merge

    hipMemsetAsync(w + zoff, 0, zero_bytes, stream);

    tbl_kernel<<<1, 128, 0, stream>>>(mtblS, btblS);
    hist_kernel<<<nb, 256, 0, stream>>>(pos, chg, cell, counts, q2_part, n);
    scan_kernel<<<1, 256, 0, stream>>>(counts, starts);
    scatter_kernel<<<nb, 256, 0, stream>>>(pos, chg, cell, starts, cursor, records, n);
    spread_bins_kernel<<<NBINS, 256, 0, stream>>>(records, starts, tiles);

    fft_z_merge<<<2048, 512, 0, stream>>>(tiles, C);                    // fwd z (DIF)
    fft_t<1><<<1024, 512, 0, stream>>>(C, KDIM, KDIM * KDIM, -1.0f);    // fwd y (DIF)
    fft_x_scale<<<NSCALE_BLK, 512, 0, stream>>>(C, cell, mtblS, btblS, scale_part);
    fft_t<0><<<1024, 512, 0, stream>>>(C, KDIM, KDIM * KDIM, 1.0f);     // inv y (DIT)
    fft_z_phi<<<2048, 512, 0, stream>>>(C, phi);                        // inv z (DIT)

    finalize_kernel<<<1, 256, 0, stream>>>(scale_part, q2_part, nb, cell, out);
    gather_kernel<<<nb, 256, 0, stream>>>(pos, chg, cell, phi, out, n);
}